// Round 10
// baseline (201.201 us; speedup 1.0000x reference)
//
#include <hip/hip_runtime.h>
#include <float.h>
#include <math.h>

#define SEQ 2048
#define NB 4
#define DIM 128
#define DL 16
#define NEGV (-1e9f)
#define TOPK 8

#define QT 128      // q-rows per out block
#define KC 64       // k chunk staged in LDS (out kernel)

typedef unsigned long long u64;
typedef __attribute__((ext_vector_type(8))) short short8;
typedef __attribute__((ext_vector_type(4))) float f32x4;

__device__ __forceinline__ void top8_insert(float* s, float key) {
    #pragma unroll
    for (int i = 0; i < 8; ++i) {
        float a = s[i];
        s[i] = fmaxf(a, key);
        key  = fminf(a, key);
    }
}

__device__ __forceinline__ float top8_merge(float* s) {
    #pragma unroll
    for (int off = 1; off < 64; off <<= 1) {
        float o[8], t[8];
        #pragma unroll
        for (int i = 0; i < 8; ++i)
            o[i] = __shfl_xor(s[i], off, 64);
        #pragma unroll
        for (int i = 0; i < 8; ++i)
            t[i] = fmaxf(s[i], o[7 - i]);
        #pragma unroll
        for (int i = 0; i < 4; ++i) {
            float a = t[i], c = t[i + 4];
            t[i] = fmaxf(a, c); t[i + 4] = fminf(a, c);
        }
        #pragma unroll
        for (int g2 = 0; g2 < 8; g2 += 4) {
            float a = t[g2], c = t[g2 + 2];
            t[g2] = fmaxf(a, c); t[g2 + 2] = fminf(a, c);
            a = t[g2 + 1]; c = t[g2 + 3];
            t[g2 + 1] = fmaxf(a, c); t[g2 + 3] = fminf(a, c);
        }
        #pragma unroll
        for (int g1 = 0; g1 < 8; g1 += 2) {
            float a = t[g1], c = t[g1 + 1];
            t[g1] = fmaxf(a, c); t[g1 + 1] = fminf(a, c);
        }
        #pragma unroll
        for (int i = 0; i < 8; ++i) s[i] = t[i];
    }
    return s[7];
}

// bf16 round-to-nearest-even of f32 (returns 16-bit pattern)
__device__ __forceinline__ unsigned bf16_rne(float x) {
    unsigned u = __float_as_uint(x);
    return (u + 0x7FFFu + ((u >> 16) & 1u)) >> 16;
}

// ---------------------------------------------------------------------------
// Kernel A: q_low/k_low projections + per-key high-rank correction scalar sh.
// ---------------------------------------------------------------------------
__global__ __launch_bounds__(256) void proj_kernel(
    const float* __restrict__ q, const float* __restrict__ k,
    const float* __restrict__ Wql, const float* __restrict__ bql,
    const float* __restrict__ Wkl, const float* __restrict__ bkl,
    const float* __restrict__ Wqh, const float* __restrict__ bqh,
    const float* __restrict__ Wkh, const float* __restrict__ bkh,
    float* __restrict__ q_low, float* __restrict__ k_low,
    float* __restrict__ sh)
{
    __shared__ float Ws[4][DIM * DL];
    __shared__ float rowq[16][DIM];
    __shared__ float rowk[16][DIM];
    int tid = threadIdx.x;
    for (int i = tid; i < DIM * DL; i += 256) {
        Ws[0][i] = Wql[i];
        Ws[1][i] = Wkl[i];
        Ws[2][i] = Wqh[i];
        Ws[3][i] = Wkh[i];
    }
    int r0 = blockIdx.x * 16;
    for (int i = tid; i < 16 * DIM; i += 256) {
        int rr = i >> 7, cc = i & 127;
        rowq[rr][cc] = q[(size_t)(r0 + rr) * DIM + cc];
        rowk[rr][cc] = k[(size_t)(r0 + rr) * DIM + cc];
    }
    __syncthreads();
    int g = tid >> 4;
    int e = tid & 15;
    float aql = 0.f, akl = 0.f, aqh = 0.f, akh = 0.f;
    #pragma unroll 8
    for (int i = 0; i < DIM; ++i) {
        float qv = rowq[g][i], kv = rowk[g][i];
        aql = fmaf(qv, Ws[0][i * DL + e], aql);
        akl = fmaf(kv, Ws[1][i * DL + e], akl);
        aqh = fmaf(qv, Ws[2][i * DL + e], aqh);
        akh = fmaf(kv, Ws[3][i * DL + e], akh);
    }
    int t = r0 + g;
    q_low[(size_t)t * DL + e] = aql + bql[e];
    k_low[(size_t)t * DL + e] = akl + bkl[e];
    float qp = aqh + bqh[e];
    float kp = akh + bkh[e];
    float prod = qp * kp;
    #pragma unroll
    for (int off = 8; off >= 1; off >>= 1)
        prod += __shfl_xor(prod, off, 16);
    if (e == 0) sh[t] = 0.25f * prod;
}

// ---------------------------------------------------------------------------
// Kernel A2: V transpose + bf16 hi/lo split: VthH/VthL[b][d][k].
// ---------------------------------------------------------------------------
__global__ __launch_bounds__(256) void vsplit_kernel(
    const float* __restrict__ V, unsigned short* __restrict__ VH,
    unsigned short* __restrict__ VL)
{
    __shared__ float T[32][33];
    int kb = blockIdx.x * 32, db = blockIdx.y * 32, b = blockIdx.z;
    int tid = threadIdx.x;
    {
        int r = tid >> 3, cg = tid & 7;
        float4 v = *(const float4*)(V + ((size_t)b * SEQ + kb + r) * DIM + db + cg * 4);
        T[r][cg * 4 + 0] = v.x; T[r][cg * 4 + 1] = v.y;
        T[r][cg * 4 + 2] = v.z; T[r][cg * 4 + 3] = v.w;
    }
    __syncthreads();
    int dr = tid >> 3, kg = tid & 7;
    unsigned h[4], l[4];
    #pragma unroll
    for (int j = 0; j < 4; ++j) {
        float f = T[kg * 4 + j][dr];
        unsigned hi = bf16_rne(f);
        float hf = __uint_as_float(hi << 16);
        unsigned lo = bf16_rne(f - hf);
        h[j] = hi; l[j] = lo;
    }
    size_t o = ((size_t)b * DIM + db + dr) * SEQ + kb + kg * 4;
    *(uint2*)(VH + o) = make_uint2(h[0] | (h[1] << 16), h[2] | (h[3] << 16));
    *(uint2*)(VL + o) = make_uint2(l[0] | (l[1] << 16), l[2] | (l[3] << 16));
}

// ---------------------------------------------------------------------------
// Kernel B v10 (unchanged from r8): v5 pass-1 + thr[row] output, no pass-2.
// ---------------------------------------------------------------------------
__global__ __launch_bounds__(256) void score_topk10(
    const float* __restrict__ q_low, const float* __restrict__ k_low,
    const int* __restrict__ valid_lens,
    float* __restrict__ Smat, float* __restrict__ thrv)
{
    __shared__ float KT[2][256 * DL];

    int tid  = threadIdx.x;
    int lane = tid & 63;
    int wv   = tid >> 6;
    int row0 = __builtin_amdgcn_readfirstlane(blockIdx.x * 8 + wv * 2);
    int b    = row0 >> 11;
    int qi0  = row0 & (SEQ - 1);
    int qi1  = qi0 + 1;

    float qv0[16], qv1[16];
    {
        const float* qp0 = q_low + (size_t)row0 * DL;
        #pragma unroll
        for (int e = 0; e < 16; ++e) { qv0[e] = qp0[e]; qv1[e] = qp0[DL + e]; }
    }

    const float4* kb4 = (const float4*)(k_low + (size_t)b * SEQ * DL);
    const int*    vlb = valid_lens + (size_t)b * SEQ;
    float* Srow0 = Smat + (size_t)row0 * SEQ;
    float* Srow1 = Srow0 + SEQ;

    float s0[8], s1[8];
    #pragma unroll
    for (int i = 0; i < 8; ++i) { s0[i] = -FLT_MAX; s1[i] = -FLT_MAX; }

    float4 stg[4];
    #pragma unroll
    for (int i = 0; i < 4; ++i) stg[i] = kb4[tid + i * 256];
    {
        float4* d = (float4*)KT[0];
        #pragma unroll
        for (int i = 0; i < 4; ++i) d[tid + i * 256] = stg[i];
    }
    __syncthreads();

    for (int c = 0; c < 8; ++c) {
        if (c < 7) {
            #pragma unroll
            for (int i = 0; i < 4; ++i)
                stg[i] = kb4[(c + 1) * 1024 + tid + i * 256];
        }
        int vli[4];
        #pragma unroll
        for (int j = 0; j < 4; ++j)
            vli[j] = vlb[c * 256 + lane + j * 64];

        const float* Kc = KT[c & 1];
        #pragma unroll
        for (int j = 0; j < 4; ++j) {
            int ccol = lane + j * 64;
            int col  = c * 256 + ccol;
            const float4* kp4 = (const float4*)(Kc + ccol * DL);
            float4 v0 = kp4[0], v1 = kp4[1], v2 = kp4[2], v3 = kp4[3];

            float a0 = 0.f, a1 = 0.f;
            a0 = fmaf(qv0[0],  v0.x, a0); a1 = fmaf(qv1[0],  v0.x, a1);
            a0 = fmaf(qv0[1],  v0.y, a0); a1 = fmaf(qv1[1],  v0.y, a1);
            a0 = fmaf(qv0[2],  v0.z, a0); a1 = fmaf(qv1[2],  v0.z, a1);
            a0 = fmaf(qv0[3],  v0.w, a0); a1 = fmaf(qv1[3],  v0.w, a1);
            a0 = fmaf(qv0[4],  v1.x, a0); a1 = fmaf(qv1[4],  v1.x, a1);
            a0 = fmaf(qv0[5],  v1.y, a0); a1 = fmaf(qv1[5],  v1.y, a1);
            a0 = fmaf(qv0[6],  v1.z, a0); a1 = fmaf(qv1[6],  v1.z, a1);
            a0 = fmaf(qv0[7],  v1.w, a0); a1 = fmaf(qv1[7],  v1.w, a1);
            a0 = fmaf(qv0[8],  v2.x, a0); a1 = fmaf(qv1[8],  v2.x, a1);
            a0 = fmaf(qv0[9],  v2.y, a0); a1 = fmaf(qv1[9],  v2.y, a1);
            a0 = fmaf(qv0[10], v2.z, a0); a1 = fmaf(qv1[10], v2.z, a1);
            a0 = fmaf(qv0[11], v2.w, a0); a1 = fmaf(qv1[11], v2.w, a1);
            a0 = fmaf(qv0[12], v3.x, a0); a1 = fmaf(qv1[12], v3.x, a1);
            a0 = fmaf(qv0[13], v3.y, a0); a1 = fmaf(qv1[13], v3.y, a1);
            a0 = fmaf(qv0[14], v3.z, a0); a1 = fmaf(qv1[14], v3.z, a1);
            a0 = fmaf(qv0[15], v3.w, a0); a1 = fmaf(qv1[15], v3.w, a1);
            a0 *= 0.25f; a1 *= 0.25f;

            int v = vli[j];
            v = v < 0 ? 0 : (v > SEQ - 1 ? SEQ - 1 : v);
            if (v == qi0) a0 += NEGV;
            if (v == qi1) a1 += NEGV;
            Srow0[col] = a0;
            Srow1[col] = a1;
            top8_insert(s0, a0);
            top8_insert(s1, a1);
        }
        if (c < 7) {
            float* d0 = KT[(c + 1) & 1];
            float4* d = (float4*)d0;
            #pragma unroll
            for (int i = 0; i < 4; ++i) d[tid + i * 256] = stg[i];
            __syncthreads();
        }
    }

    float t80 = top8_merge(s0);
    float t81 = top8_merge(s1);
    if (lane == 0) {
        thrv[row0]     = t80;
        thrv[row0 + 1] = t81;
    }
}

// ---------------------------------------------------------------------------
// Kernel C1 v2: column softmax partials over lazily-patched S, float4
// vectorized: each thread owns 4 adjacent columns (16 B/lane loads, 1 KB per
// wave instruction) and runs 4 INDEPENDENT online-softmax chains (4x ILP on
// the serial fmax->exp->fma chain that limited the scalar version).
// Partials interleaved (m,l) float2 -> 32 B contiguous store per thread.
// ---------------------------------------------------------------------------
__global__ __launch_bounds__(256) void colred_partial4(
    const float* __restrict__ Smat, const float* __restrict__ thrv,
    const float* __restrict__ sh, float2* __restrict__ pml, int qch)
{
    int kbase = blockIdx.x * 1024 + threadIdx.x * 4;
    int qc = blockIdx.y;
    int b  = blockIdx.z;
    const float* Sp  = Smat + (size_t)b * SEQ * SEQ + (size_t)(qc * qch) * SEQ + kbase;
    const float* thb = thrv + (size_t)b * SEQ + qc * qch;
    float4 shk = *(const float4*)(sh + (size_t)b * SEQ + kbase);

    float m0 = -FLT_MAX, m1 = -FLT_MAX, m2 = -FLT_MAX, m3 = -FLT_MAX;
    float l0 = 0.f, l1 = 0.f, l2 = 0.f, l3 = 0.f;
    for (int qq = 0; qq < qch; ++qq) {
        float4 v = *(const float4*)(Sp + (size_t)qq * SEQ);
        float t = thb[qq];                       // wave-uniform scalar
        float e0 = (v.x >= t) ? shk.x : v.x;     // lazy top-8 patch
        float e1 = (v.y >= t) ? shk.y : v.y;
        float e2 = (v.z >= t) ? shk.z : v.z;
        float e3 = (v.w >= t) ? shk.w : v.w;
        float n0 = fmaxf(m0, e0), n1 = fmaxf(m1, e1);
        float n2 = fmaxf(m2, e2), n3 = fmaxf(m3, e3);
        l0 = l0 * __expf(m0 - n0) + __expf(e0 - n0);
        l1 = l1 * __expf(m1 - n1) + __expf(e1 - n1);
        l2 = l2 * __expf(m2 - n2) + __expf(e2 - n2);
        l3 = l3 * __expf(m3 - n3) + __expf(e3 - n3);
        m0 = n0; m1 = n1; m2 = n2; m3 = n3;
    }
    int nch = gridDim.y;
    float2* o = pml + ((size_t)b * nch + qc) * SEQ + kbase;
    o[0] = make_float2(m0, l0);
    o[1] = make_float2(m1, l1);
    o[2] = make_float2(m2, l2);
    o[3] = make_float2(m3, l3);
}

__global__ __launch_bounds__(256) void colred_final(
    const float2* __restrict__ pml,
    float* __restrict__ cmax, float* __restrict__ cinv, int nch)
{
    int idx = blockIdx.x * 256 + threadIdx.x;
    int b = idx >> 11, kcol = idx & (SEQ - 1);
    float m = -FLT_MAX, l = 0.f;
    for (int c = 0; c < nch; ++c) {
        float2 p = pml[((size_t)b * nch + c) * SEQ + kcol];
        float nm = fmaxf(m, p.x);
        l = l * __expf(m - nm) + p.y * __expf(p.x - nm);
        m = nm;
    }
    cmax[idx] = m;
    cinv[idx] = 1.f / l;
}

// ---------------------------------------------------------------------------
// Kernel D (unchanged from r8): MFMA PV with lazy patch.
// ---------------------------------------------------------------------------
__global__ __launch_bounds__(256) void out_mfma(
    const float* __restrict__ Smat, const unsigned short* __restrict__ VH,
    const unsigned short* __restrict__ VL,
    const float* __restrict__ cmax, const float* __restrict__ cinv,
    const float* __restrict__ thrv, const float* __restrict__ sh,
    float* __restrict__ dst, int krange)
{
    __shared__ unsigned int VtH[DIM * 32];   // 16 KB, [d][k-words] XOR-swizzled
    __shared__ unsigned int VtL[DIM * 32];   // 16 KB

    int tid  = threadIdx.x;
    int w    = tid >> 6;
    int lane = tid & 63;
    int ln   = lane & 15;
    int quad = lane >> 4;
    int q0   = blockIdx.x * QT;
    int ksid = blockIdx.y;
    int b    = blockIdx.z;
    int kbeg = ksid * krange;

    const float* Sb = Smat + (size_t)b * SEQ * SEQ;
    const unsigned short* VHb = VH + (size_t)b * DIM * SEQ;
    const unsigned short* VLb = VL + (size_t)b * DIM * SEQ;
    const float* cm  = cmax + (size_t)b * SEQ;
    const float* ci  = cinv + (size_t)b * SEQ;
    const float* shb = sh + (size_t)b * SEQ;

    float thrm[2];
    #pragma unroll
    for (int mt = 0; mt < 2; ++mt)
        thrm[mt] = thrv[(size_t)b * SEQ + q0 + w * 32 + mt * 16 + ln];

    f32x4 acc[2][8];
    #pragma unroll
    for (int mt = 0; mt < 2; ++mt)
        #pragma unroll
        for (int nt = 0; nt < 8; ++nt)
            acc[mt][nt] = (f32x4){0.f, 0.f, 0.f, 0.f};

    int sd0   = tid >> 3;   // staging d row (0..31, +32/iter)
    int skseg = tid & 7;    // staging k-segment (16B granule)

    for (int k0 = kbeg; k0 < kbeg + krange; k0 += KC) {
        // stage V^T hi/lo chunk [128d][64k] bf16, XOR-swizzled 16B granules
        #pragma unroll
        for (int it = 0; it < 4; ++it) {
            int d = sd0 + it * 32;
            size_t go = (size_t)d * SEQ + k0 + skseg * 8;
            uint4 hv = *(const uint4*)(VHb + go);
            uint4 lv = *(const uint4*)(VLb + go);
            int wa = d * 32 + ((skseg ^ (d & 7)) << 2);
            *(uint4*)&VtH[wa] = hv;
            *(uint4*)&VtL[wa] = lv;
        }

        // P A-fragments (registers): lane holds P[q=mtile+ln][k=quad*8+j]
        short8 Ah[2][2], Al[2][2];
        #pragma unroll
        for (int ks = 0; ks < 2; ++ks) {
            int kk = k0 + ks * 32 + quad * 8;
            float4 cma = *(const float4*)(cm + kk);
            float4 cmb = *(const float4*)(cm + kk + 4);
            float4 cia = *(const float4*)(ci + kk);
            float4 cib = *(const float4*)(ci + kk + 4);
            float4 sha = *(const float4*)(shb + kk);
            float4 shx = *(const float4*)(shb + kk + 4);
            #pragma unroll
            for (int mt = 0; mt < 2; ++mt) {
                const float* Sp = Sb + (size_t)(q0 + w * 32 + mt * 16 + ln) * SEQ + kk;
                float4 sa = *(const float4*)Sp;
                float4 sb = *(const float4*)(Sp + 4);
                float t = thrm[mt];
                float e0 = (sa.x >= t) ? sha.x : sa.x;
                float e1 = (sa.y >= t) ? sha.y : sa.y;
                float e2 = (sa.z >= t) ? sha.z : sa.z;
                float e3 = (sa.w >= t) ? sha.w : sa.w;
                float e4 = (sb.x >= t) ? shx.x : sb.x;
                float e5 = (sb.y >= t) ? shx.y : sb.y;
                float e6 = (sb.z >= t) ? shx.z : sb.z;
                float e7 = (sb.w >= t) ? shx.w : sb.w;
                float p[8];
                p[0] = __expf(e0 - cma.x) * cia.x;
                p[1] = __expf(e1 - cma.y) * cia.y;
                p[2] = __expf(e2 - cma.z) * cia.z;
                p[3] = __expf(e3 - cma.w) * cia.w;
                p[4] = __expf(e4 - cmb.x) * cib.x;
                p[5] = __expf(e5 - cmb.y) * cib.y;
                p[6] = __expf(e6 - cmb.z) * cib.z;
                p[7] = __expf(e7 - cmb.w) * cib.w;
                #pragma unroll
                for (int j = 0; j < 8; ++j) {
                    unsigned hi = bf16_rne(p[j]);
                    float hf = __uint_as_float(hi << 16);
                    unsigned lo = bf16_rne(p[j] - hf);
                    Ah[mt][ks][j] = (short)hi;
                    Al[mt][ks][j] = (short)lo;
                }
            }
        }
        __syncthreads();

        #pragma unroll
        for (int nt = 0; nt < 8; ++nt) {
            int d = nt * 16 + ln;
            #pragma unroll
            for (int ks = 0; ks < 2; ++ks) {
                int kseg = ks * 4 + quad;
                int wa = d * 32 + ((kseg ^ (d & 7)) << 2);
                short8 bh = *(short8*)&VtH[wa];
                short8 bl = *(short8*)&VtL[wa];
                #pragma unroll
                for (int mt = 0; mt < 2; ++mt) {
                    acc[mt][nt] = __builtin_amdgcn_mfma_f32_16x16x32_bf16(
                        Ah[mt][ks], bh, acc[mt][nt], 0, 0, 0);
                    acc[mt][nt] = __builtin_amdgcn_mfma_f32_16x16x32_bf16(
                        Al[mt][ks], bh, acc[mt][nt], 0, 0, 0);
                    acc[mt][nt] = __builtin_amdgcn_mfma_f32_16x16x32_bf16(
                        Ah[mt][ks], bl, acc[mt][nt], 0, 0, 0);
                }
            }
        }
        __syncthreads();
    }

    float* dp = dst + (size_t)ksid * ((size_t)NB * SEQ * DIM)
                    + (size_t)b * SEQ * DIM;
    #pragma unroll
    for (int mt = 0; mt < 2; ++mt) {
        #pragma unroll
        for (int r = 0; r < 4; ++r) {
            float* o = dp + (size_t)(q0 + w * 32 + mt * 16 + quad * 4 + r) * DIM + ln;
            #pragma unroll
            for (int nt = 0; nt < 8; ++nt)
                o[nt * 16] = acc[mt][nt][r];
        }
    }
}

__global__ __launch_bounds__(256) void reduce_kernel(
    const float* __restrict__ part, float* __restrict__ out, int ksplit)
{
    int idx = blockIdx.x * 256 + threadIdx.x;
    const float4* p = (const float4*)part;
    float4 a = p[idx];
    for (int s = 1; s < ksplit; ++s) {
        float4 q = p[(size_t)idx + (size_t)s * 262144];
        a.x += q.x; a.y += q.y; a.z += q.z; a.w += q.w;
    }
    ((float4*)out)[idx] = a;
}

extern "C" void kernel_launch(void* const* d_in, const int* in_sizes, int n_in,
                              void* d_out, int out_size, void* d_ws, size_t ws_size,
                              hipStream_t stream)
{
    const float* queries = (const float*)d_in[0];
    const float* keys    = (const float*)d_in[1];
    const float* values  = (const float*)d_in[2];
    const int*   valid   = (const int*)d_in[3];
    const float* Wql = (const float*)d_in[4];
    const float* bql = (const float*)d_in[5];
    const float* Wkl = (const float*)d_in[6];
    const float* bkl = (const float*)d_in[7];
    const float* Wqh = (const float*)d_in[8];
    const float* bqh = (const float*)d_in[9];
    const float* Wkh = (const float*)d_in[10];
    const float* bkh = (const float*)d_in[11];

    char* ws = (char*)d_ws;
    float* Smat  = (float*)(ws);                        // 64 MB
    float* q_low = (float*)(ws + 67108864);             // 512 KB
    float* k_low = (float*)(ws + 67633152);             // 512 KB
    float* sh    = (float*)(ws + 68157440);             // 32 KB
    float* thrv  = (float*)(ws + 68190208);             // 32 KB (per-row top-8 threshold)
    float* cmax  = (float*)(ws + 68222976);             // 32 KB
    float* cinv  = (float*)(ws + 68255744);             // 32 KB
    unsigned short* VthH = (unsigned short*)(ws + 68288512);  // 2 MB
    unsigned short* VthL = (unsigned short*)(ws + 70385664);  // 2 MB -> ends 72482816
    // pml lives only until colred_final; it overlaps the part region, which
    // is written only afterwards (stream-ordered).
    const size_t part_off = 72482816;
    float2* pml  = (float2*)(ws + part_off);            // nch==128: 8 MB, nch==32: 2 MB
    float* part  = (float*)(ws + part_off);             // ksplit*4 MB

    const size_t part_sz  = (size_t)NB * SEQ * DIM * 4;  // 4 MB
    int ksplit = 1;
    if      (ws_size >= part_off + 8 * part_sz) ksplit = 8;
    else if (ws_size >= part_off + 4 * part_sz) ksplit = 4;
    else if (ws_size >= part_off + 2 * part_sz) ksplit = 2;

    // 128 chunks (QCH=16) needs 8 MB of pml; fall back to 32 chunks (2 MB).
    int nch = (ws_size >= part_off + 8388608) ? 128 : 32;
    int qch = SEQ / nch;

    proj_kernel<<<dim3((NB * SEQ) / 16), 256, 0, stream>>>(
        queries, keys, Wql, bql, Wkl, bkl, Wqh, bqh, Wkh, bkh, q_low, k_low, sh);

    vsplit_kernel<<<dim3(SEQ / 32, DIM / 32, NB), 256, 0, stream>>>(
        values, VthH, VthL);

    score_topk10<<<dim3((NB * SEQ) / 8), 256, 0, stream>>>(
        q_low, k_low, valid, Smat, thrv);

    colred_partial4<<<dim3(SEQ / 1024, nch, NB), 256, 0, stream>>>(
        Smat, thrv, sh, pml, qch);

    colred_final<<<dim3((NB * SEQ) / 256), 256, 0, stream>>>(pml, cmax, cinv, nch);

    if (ksplit == 1) {
        out_mfma<<<dim3(SEQ / QT, 1, NB), 256, 0, stream>>>(
            Smat, VthH, VthL, cmax, cinv, thrv, sh, (float*)d_out, SEQ);
    } else {
        out_mfma<<<dim3(SEQ / QT, ksplit, NB), 256, 0, stream>>>(
            Smat, VthH, VthL, cmax, cinv, thrv, sh, part, SEQ / ksplit);
        reduce_kernel<<<(NB * SEQ * DIM / 4) / 256, 256, 0, stream>>>(
            part, (float*)d_out, ksplit);
    }
}

// Round 11
// 167.594 us; speedup vs baseline: 1.2005x; 1.2005x over previous
//
#include <hip/hip_runtime.h>
#include <float.h>
#include <math.h>

#define SEQ 2048
#define NB 4
#define DIM 128
#define DL 16
#define NEGV (-1e9f)
#define TOPK 8

#define QT 128      // q-rows per out block
#define KC 64       // k chunk staged in LDS (out kernel)
#define QCH 64      // q-chunk for colred

typedef unsigned long long u64;
typedef __attribute__((ext_vector_type(8))) short short8;
typedef __attribute__((ext_vector_type(4))) float f32x4;

__device__ __forceinline__ void top8_insert(float* s, float key) {
    #pragma unroll
    for (int i = 0; i < 8; ++i) {
        float a = s[i];
        s[i] = fmaxf(a, key);
        key  = fminf(a, key);
    }
}

__device__ __forceinline__ float top8_merge(float* s) {
    #pragma unroll
    for (int off = 1; off < 64; off <<= 1) {
        float o[8], t[8];
        #pragma unroll
        for (int i = 0; i < 8; ++i)
            o[i] = __shfl_xor(s[i], off, 64);
        #pragma unroll
        for (int i = 0; i < 8; ++i)
            t[i] = fmaxf(s[i], o[7 - i]);
        #pragma unroll
        for (int i = 0; i < 4; ++i) {
            float a = t[i], c = t[i + 4];
            t[i] = fmaxf(a, c); t[i + 4] = fminf(a, c);
        }
        #pragma unroll
        for (int g2 = 0; g2 < 8; g2 += 4) {
            float a = t[g2], c = t[g2 + 2];
            t[g2] = fmaxf(a, c); t[g2 + 2] = fminf(a, c);
            a = t[g2 + 1]; c = t[g2 + 3];
            t[g2 + 1] = fmaxf(a, c); t[g2 + 3] = fminf(a, c);
        }
        #pragma unroll
        for (int g1 = 0; g1 < 8; g1 += 2) {
            float a = t[g1], c = t[g1 + 1];
            t[g1] = fmaxf(a, c); t[g1 + 1] = fminf(a, c);
        }
        #pragma unroll
        for (int i = 0; i < 8; ++i) s[i] = t[i];
    }
    return s[7];
}

// bf16 round-to-nearest-even of f32 (returns 16-bit pattern)
__device__ __forceinline__ unsigned bf16_rne(float x) {
    unsigned u = __float_as_uint(x);
    return (u + 0x7FFFu + ((u >> 16) & 1u)) >> 16;
}

// ---------------------------------------------------------------------------
// Kernel A: q_low/k_low projections + per-key high-rank correction scalar sh.
// (sh[k] depends only on key k — reference gathers queries[topk_idx] too, so
// score_high = dot(Wqh^T q[k], Wkh^T k[k]) is row-independent.)
// ---------------------------------------------------------------------------
__global__ __launch_bounds__(256) void proj_kernel(
    const float* __restrict__ q, const float* __restrict__ k,
    const float* __restrict__ Wql, const float* __restrict__ bql,
    const float* __restrict__ Wkl, const float* __restrict__ bkl,
    const float* __restrict__ Wqh, const float* __restrict__ bqh,
    const float* __restrict__ Wkh, const float* __restrict__ bkh,
    float* __restrict__ q_low, float* __restrict__ k_low,
    float* __restrict__ sh)
{
    __shared__ float Ws[4][DIM * DL];
    __shared__ float rowq[16][DIM];
    __shared__ float rowk[16][DIM];
    int tid = threadIdx.x;
    for (int i = tid; i < DIM * DL; i += 256) {
        Ws[0][i] = Wql[i];
        Ws[1][i] = Wkl[i];
        Ws[2][i] = Wqh[i];
        Ws[3][i] = Wkh[i];
    }
    int r0 = blockIdx.x * 16;
    for (int i = tid; i < 16 * DIM; i += 256) {
        int rr = i >> 7, cc = i & 127;
        rowq[rr][cc] = q[(size_t)(r0 + rr) * DIM + cc];
        rowk[rr][cc] = k[(size_t)(r0 + rr) * DIM + cc];
    }
    __syncthreads();
    int g = tid >> 4;
    int e = tid & 15;
    float aql = 0.f, akl = 0.f, aqh = 0.f, akh = 0.f;
    #pragma unroll 8
    for (int i = 0; i < DIM; ++i) {
        float qv = rowq[g][i], kv = rowk[g][i];
        aql = fmaf(qv, Ws[0][i * DL + e], aql);
        akl = fmaf(kv, Ws[1][i * DL + e], akl);
        aqh = fmaf(qv, Ws[2][i * DL + e], aqh);
        akh = fmaf(kv, Ws[3][i * DL + e], akh);
    }
    int t = r0 + g;
    q_low[(size_t)t * DL + e] = aql + bql[e];
    k_low[(size_t)t * DL + e] = akl + bkl[e];
    float qp = aqh + bqh[e];
    float kp = akh + bkh[e];
    float prod = qp * kp;
    #pragma unroll
    for (int off = 8; off >= 1; off >>= 1)
        prod += __shfl_xor(prod, off, 16);
    if (e == 0) sh[t] = 0.25f * prod;
}

// ---------------------------------------------------------------------------
// Kernel A2: V transpose + bf16 hi/lo split: VthH/VthL[b][d][k].
// ---------------------------------------------------------------------------
__global__ __launch_bounds__(256) void vsplit_kernel(
    const float* __restrict__ V, unsigned short* __restrict__ VH,
    unsigned short* __restrict__ VL)
{
    __shared__ float T[32][33];
    int kb = blockIdx.x * 32, db = blockIdx.y * 32, b = blockIdx.z;
    int tid = threadIdx.x;
    {
        int r = tid >> 3, cg = tid & 7;
        float4 v = *(const float4*)(V + ((size_t)b * SEQ + kb + r) * DIM + db + cg * 4);
        T[r][cg * 4 + 0] = v.x; T[r][cg * 4 + 1] = v.y;
        T[r][cg * 4 + 2] = v.z; T[r][cg * 4 + 3] = v.w;
    }
    __syncthreads();
    int dr = tid >> 3, kg = tid & 7;
    unsigned h[4], l[4];
    #pragma unroll
    for (int j = 0; j < 4; ++j) {
        float f = T[kg * 4 + j][dr];
        unsigned hi = bf16_rne(f);
        float hf = __uint_as_float(hi << 16);
        unsigned lo = bf16_rne(f - hf);
        h[j] = hi; l[j] = lo;
    }
    size_t o = ((size_t)b * DIM + db + dr) * SEQ + kb + kg * 4;
    *(uint2*)(VH + o) = make_uint2(h[0] | (h[1] << 16), h[2] | (h[3] << 16));
    *(uint2*)(VL + o) = make_uint2(l[0] | (l[1] << 16), l[2] | (l[3] << 16));
}

// ---------------------------------------------------------------------------
// Kernel B v10: v5 pass-1 EXACTLY (4 waves x 2 rows, 2-buffer LDS pipeline,
// scores -> Smat + value-only top-8), but pass-2 is DELETED: instead of
// patching S in memory (32 MB HBM re-read + scatter), the 8th-largest value
// per row is written to thr[row]; colred/out apply the patch lazily via
// (S >= thr[q]) ? sh[k] : S  — same rule as the old c_ge==8 fast path.
// ---------------------------------------------------------------------------
__global__ __launch_bounds__(256) void score_topk10(
    const float* __restrict__ q_low, const float* __restrict__ k_low,
    const int* __restrict__ valid_lens,
    float* __restrict__ Smat, float* __restrict__ thrv)
{
    __shared__ float KT[2][256 * DL];

    int tid  = threadIdx.x;
    int lane = tid & 63;
    int wv   = tid >> 6;
    int row0 = __builtin_amdgcn_readfirstlane(blockIdx.x * 8 + wv * 2);
    int b    = row0 >> 11;
    int qi0  = row0 & (SEQ - 1);
    int qi1  = qi0 + 1;

    float qv0[16], qv1[16];
    {
        const float* qp0 = q_low + (size_t)row0 * DL;
        #pragma unroll
        for (int e = 0; e < 16; ++e) { qv0[e] = qp0[e]; qv1[e] = qp0[DL + e]; }
    }

    const float4* kb4 = (const float4*)(k_low + (size_t)b * SEQ * DL);
    const int*    vlb = valid_lens + (size_t)b * SEQ;
    float* Srow0 = Smat + (size_t)row0 * SEQ;
    float* Srow1 = Srow0 + SEQ;

    float s0[8], s1[8];
    #pragma unroll
    for (int i = 0; i < 8; ++i) { s0[i] = -FLT_MAX; s1[i] = -FLT_MAX; }

    float4 stg[4];
    #pragma unroll
    for (int i = 0; i < 4; ++i) stg[i] = kb4[tid + i * 256];
    {
        float4* d = (float4*)KT[0];
        #pragma unroll
        for (int i = 0; i < 4; ++i) d[tid + i * 256] = stg[i];
    }
    __syncthreads();

    for (int c = 0; c < 8; ++c) {
        if (c < 7) {
            #pragma unroll
            for (int i = 0; i < 4; ++i)
                stg[i] = kb4[(c + 1) * 1024 + tid + i * 256];
        }
        int vli[4];
        #pragma unroll
        for (int j = 0; j < 4; ++j)
            vli[j] = vlb[c * 256 + lane + j * 64];

        const float* Kc = KT[c & 1];
        #pragma unroll
        for (int j = 0; j < 4; ++j) {
            int ccol = lane + j * 64;
            int col  = c * 256 + ccol;
            const float4* kp4 = (const float4*)(Kc + ccol * DL);
            float4 v0 = kp4[0], v1 = kp4[1], v2 = kp4[2], v3 = kp4[3];

            float a0 = 0.f, a1 = 0.f;
            a0 = fmaf(qv0[0],  v0.x, a0); a1 = fmaf(qv1[0],  v0.x, a1);
            a0 = fmaf(qv0[1],  v0.y, a0); a1 = fmaf(qv1[1],  v0.y, a1);
            a0 = fmaf(qv0[2],  v0.z, a0); a1 = fmaf(qv1[2],  v0.z, a1);
            a0 = fmaf(qv0[3],  v0.w, a0); a1 = fmaf(qv1[3],  v0.w, a1);
            a0 = fmaf(qv0[4],  v1.x, a0); a1 = fmaf(qv1[4],  v1.x, a1);
            a0 = fmaf(qv0[5],  v1.y, a0); a1 = fmaf(qv1[5],  v1.y, a1);
            a0 = fmaf(qv0[6],  v1.z, a0); a1 = fmaf(qv1[6],  v1.z, a1);
            a0 = fmaf(qv0[7],  v1.w, a0); a1 = fmaf(qv1[7],  v1.w, a1);
            a0 = fmaf(qv0[8],  v2.x, a0); a1 = fmaf(qv1[8],  v2.x, a1);
            a0 = fmaf(qv0[9],  v2.y, a0); a1 = fmaf(qv1[9],  v2.y, a1);
            a0 = fmaf(qv0[10], v2.z, a0); a1 = fmaf(qv1[10], v2.z, a1);
            a0 = fmaf(qv0[11], v2.w, a0); a1 = fmaf(qv1[11], v2.w, a1);
            a0 = fmaf(qv0[12], v3.x, a0); a1 = fmaf(qv1[12], v3.x, a1);
            a0 = fmaf(qv0[13], v3.y, a0); a1 = fmaf(qv1[13], v3.y, a1);
            a0 = fmaf(qv0[14], v3.z, a0); a1 = fmaf(qv1[14], v3.z, a1);
            a0 = fmaf(qv0[15], v3.w, a0); a1 = fmaf(qv1[15], v3.w, a1);
            a0 *= 0.25f; a1 *= 0.25f;

            int v = vli[j];
            v = v < 0 ? 0 : (v > SEQ - 1 ? SEQ - 1 : v);
            if (v == qi0) a0 += NEGV;
            if (v == qi1) a1 += NEGV;
            Srow0[col] = a0;
            Srow1[col] = a1;
            top8_insert(s0, a0);
            top8_insert(s1, a1);
        }
        if (c < 7) {
            float* d0 = KT[(c + 1) & 1];
            float4* d = (float4*)d0;
            #pragma unroll
            for (int i = 0; i < 4; ++i) d[tid + i * 256] = stg[i];
            __syncthreads();
        }
    }

    float t80 = top8_merge(s0);
    float t81 = top8_merge(s1);
    if (lane == 0) {
        thrv[row0]     = t80;
        thrv[row0 + 1] = t81;
    }
}

// ---------------------------------------------------------------------------
// Kernel C1/C2: column (q-axis) softmax stats over the LAZILY-PATCHED S:
// v_eff = (S >= thr[q]) ? sh[k] : S. Compile-time trip counts (QCH/32) —
// runtime bounds here cost +33us (r10): the unrolled load batch is the win.
// ---------------------------------------------------------------------------
__global__ __launch_bounds__(256) void colred_partial(
    const float* __restrict__ Smat, const float* __restrict__ thrv,
    const float* __restrict__ sh,
    float* __restrict__ pm, float* __restrict__ pl)
{
    int kcol = blockIdx.x * 256 + threadIdx.x;
    int qc = blockIdx.y;
    int b  = blockIdx.z;
    const float* Sp  = Smat + (size_t)b * SEQ * SEQ + (size_t)(qc * QCH) * SEQ + kcol;
    const float* thb = thrv + (size_t)b * SEQ + qc * QCH;
    float shk = sh[(size_t)b * SEQ + kcol];
    float m = -FLT_MAX, l = 0.f;
    #pragma unroll 4
    for (int qq = 0; qq < QCH; ++qq) {
        float v = Sp[(size_t)qq * SEQ];
        float t = thb[qq];                 // wave-uniform scalar
        v = (v >= t) ? shk : v;            // lazy top-8 patch
        float nm = fmaxf(m, v);
        l = l * __expf(m - nm) + __expf(v - nm);
        m = nm;
    }
    pm[((size_t)b * 32 + qc) * SEQ + kcol] = m;
    pl[((size_t)b * 32 + qc) * SEQ + kcol] = l;
}

__global__ __launch_bounds__(256) void colred_final(
    const float* __restrict__ pm, const float* __restrict__ pl,
    float* __restrict__ cmax, float* __restrict__ cinv)
{
    int idx = blockIdx.x * 256 + threadIdx.x;
    int b = idx >> 11, kcol = idx & (SEQ - 1);
    float m = -FLT_MAX, l = 0.f;
    #pragma unroll
    for (int c = 0; c < 32; ++c) {
        float mm = pm[((size_t)b * 32 + c) * SEQ + kcol];
        float ll = pl[((size_t)b * 32 + c) * SEQ + kcol];
        float nm = fmaxf(m, mm);
        l = l * __expf(m - nm) + ll * __expf(mm - nm);
        m = nm;
    }
    cmax[idx] = m;
    cinv[idx] = 1.f / l;
}

// ---------------------------------------------------------------------------
// Kernel D (r0 single-buffer version + lazy patch): MFMA PV. Block = 128q x
// 128d, k-chunks of 64, ksplit partials. P = exp(((S>=thr[q])?sh[k]:S) -
// cmax[k]) * cinv[k], generated in registers (hi/lo bf16 split); V^T hi/lo
// staged in XOR-swizzled LDS. out = PhVh + PlVh + PhVl.
// ---------------------------------------------------------------------------
__global__ __launch_bounds__(256) void out_mfma(
    const float* __restrict__ Smat, const unsigned short* __restrict__ VH,
    const unsigned short* __restrict__ VL,
    const float* __restrict__ cmax, const float* __restrict__ cinv,
    const float* __restrict__ thrv, const float* __restrict__ sh,
    float* __restrict__ dst, int krange)
{
    __shared__ unsigned int VtH[DIM * 32];   // 16 KB, [d][k-words] XOR-swizzled
    __shared__ unsigned int VtL[DIM * 32];   // 16 KB

    int tid  = threadIdx.x;
    int w    = tid >> 6;
    int lane = tid & 63;
    int ln   = lane & 15;
    int quad = lane >> 4;
    int q0   = blockIdx.x * QT;
    int ksid = blockIdx.y;
    int b    = blockIdx.z;
    int kbeg = ksid * krange;

    const float* Sb = Smat + (size_t)b * SEQ * SEQ;
    const unsigned short* VHb = VH + (size_t)b * DIM * SEQ;
    const unsigned short* VLb = VL + (size_t)b * DIM * SEQ;
    const float* cm  = cmax + (size_t)b * SEQ;
    const float* ci  = cinv + (size_t)b * SEQ;
    const float* shb = sh + (size_t)b * SEQ;

    float thrm[2];
    #pragma unroll
    for (int mt = 0; mt < 2; ++mt)
        thrm[mt] = thrv[(size_t)b * SEQ + q0 + w * 32 + mt * 16 + ln];

    f32x4 acc[2][8];
    #pragma unroll
    for (int mt = 0; mt < 2; ++mt)
        #pragma unroll
        for (int nt = 0; nt < 8; ++nt)
            acc[mt][nt] = (f32x4){0.f, 0.f, 0.f, 0.f};

    int sd0   = tid >> 3;   // staging d row (0..31, +32/iter)
    int skseg = tid & 7;    // staging k-segment (16B granule)

    for (int k0 = kbeg; k0 < kbeg + krange; k0 += KC) {
        // stage V^T hi/lo chunk [128d][64k] bf16, XOR-swizzled 16B granules
        #pragma unroll
        for (int it = 0; it < 4; ++it) {
            int d = sd0 + it * 32;
            size_t go = (size_t)d * SEQ + k0 + skseg * 8;
            uint4 hv = *(const uint4*)(VHb + go);
            uint4 lv = *(const uint4*)(VLb + go);
            int wa = d * 32 + ((skseg ^ (d & 7)) << 2);
            *(uint4*)&VtH[wa] = hv;
            *(uint4*)&VtL[wa] = lv;
        }

        // P A-fragments (registers): lane holds P[q=mtile+ln][k=quad*8+j]
        short8 Ah[2][2], Al[2][2];
        #pragma unroll
        for (int ks = 0; ks < 2; ++ks) {
            int kk = k0 + ks * 32 + quad * 8;
            float4 cma = *(const float4*)(cm + kk);
            float4 cmb = *(const float4*)(cm + kk + 4);
            float4 cia = *(const float4*)(ci + kk);
            float4 cib = *(const float4*)(ci + kk + 4);
            float4 sha = *(const float4*)(shb + kk);
            float4 shx = *(const float4*)(shb + kk + 4);
            #pragma unroll
            for (int mt = 0; mt < 2; ++mt) {
                const float* Sp = Sb + (size_t)(q0 + w * 32 + mt * 16 + ln) * SEQ + kk;
                float4 sa = *(const float4*)Sp;
                float4 sb = *(const float4*)(Sp + 4);
                float t = thrm[mt];
                float e0 = (sa.x >= t) ? sha.x : sa.x;
                float e1 = (sa.y >= t) ? sha.y : sa.y;
                float e2 = (sa.z >= t) ? sha.z : sa.z;
                float e3 = (sa.w >= t) ? sha.w : sa.w;
                float e4 = (sb.x >= t) ? shx.x : sb.x;
                float e5 = (sb.y >= t) ? shx.y : sb.y;
                float e6 = (sb.z >= t) ? shx.z : sb.z;
                float e7 = (sb.w >= t) ? shx.w : sb.w;
                float p[8];
                p[0] = __expf(e0 - cma.x) * cia.x;
                p[1] = __expf(e1 - cma.y) * cia.y;
                p[2] = __expf(e2 - cma.z) * cia.z;
                p[3] = __expf(e3 - cma.w) * cia.w;
                p[4] = __expf(e4 - cmb.x) * cib.x;
                p[5] = __expf(e5 - cmb.y) * cib.y;
                p[6] = __expf(e6 - cmb.z) * cib.z;
                p[7] = __expf(e7 - cmb.w) * cib.w;
                #pragma unroll
                for (int j = 0; j < 8; ++j) {
                    unsigned hi = bf16_rne(p[j]);
                    float hf = __uint_as_float(hi << 16);
                    unsigned lo = bf16_rne(p[j] - hf);
                    Ah[mt][ks][j] = (short)hi;
                    Al[mt][ks][j] = (short)lo;
                }
            }
        }
        __syncthreads();

        #pragma unroll
        for (int nt = 0; nt < 8; ++nt) {
            int d = nt * 16 + ln;
            #pragma unroll
            for (int ks = 0; ks < 2; ++ks) {
                int kseg = ks * 4 + quad;
                int wa = d * 32 + ((kseg ^ (d & 7)) << 2);
                short8 bh = *(short8*)&VtH[wa];
                short8 bl = *(short8*)&VtL[wa];
                #pragma unroll
                for (int mt = 0; mt < 2; ++mt) {
                    acc[mt][nt] = __builtin_amdgcn_mfma_f32_16x16x32_bf16(
                        Ah[mt][ks], bh, acc[mt][nt], 0, 0, 0);
                    acc[mt][nt] = __builtin_amdgcn_mfma_f32_16x16x32_bf16(
                        Al[mt][ks], bh, acc[mt][nt], 0, 0, 0);
                    acc[mt][nt] = __builtin_amdgcn_mfma_f32_16x16x32_bf16(
                        Ah[mt][ks], bl, acc[mt][nt], 0, 0, 0);
                }
            }
        }
        __syncthreads();
    }

    float* dp = dst + (size_t)ksid * ((size_t)NB * SEQ * DIM)
                    + (size_t)b * SEQ * DIM;
    #pragma unroll
    for (int mt = 0; mt < 2; ++mt) {
        #pragma unroll
        for (int r = 0; r < 4; ++r) {
            float* o = dp + (size_t)(q0 + w * 32 + mt * 16 + quad * 4 + r) * DIM + ln;
            #pragma unroll
            for (int nt = 0; nt < 8; ++nt)
                o[nt * 16] = acc[mt][nt][r];
        }
    }
}

__global__ __launch_bounds__(256) void reduce_kernel(
    const float* __restrict__ part, float* __restrict__ out, int ksplit)
{
    int idx = blockIdx.x * 256 + threadIdx.x;
    const float4* p = (const float4*)part;
    float4 a = p[idx];
    for (int s = 1; s < ksplit; ++s) {
        float4 q = p[(size_t)idx + (size_t)s * 262144];
        a.x += q.x; a.y += q.y; a.z += q.z; a.w += q.w;
    }
    ((float4*)out)[idx] = a;
}

extern "C" void kernel_launch(void* const* d_in, const int* in_sizes, int n_in,
                              void* d_out, int out_size, void* d_ws, size_t ws_size,
                              hipStream_t stream)
{
    const float* queries = (const float*)d_in[0];
    const float* keys    = (const float*)d_in[1];
    const float* values  = (const float*)d_in[2];
    const int*   valid   = (const int*)d_in[3];
    const float* Wql = (const float*)d_in[4];
    const float* bql = (const float*)d_in[5];
    const float* Wkl = (const float*)d_in[6];
    const float* bkl = (const float*)d_in[7];
    const float* Wqh = (const float*)d_in[8];
    const float* bqh = (const float*)d_in[9];
    const float* Wkh = (const float*)d_in[10];
    const float* bkh = (const float*)d_in[11];

    char* ws = (char*)d_ws;
    float* Smat  = (float*)(ws);                        // 64 MB
    float* q_low = (float*)(ws + 67108864);             // 512 KB
    float* k_low = (float*)(ws + 67633152);             // 512 KB
    float* sh    = (float*)(ws + 68157440);             // 32 KB
    float* thrv  = (float*)(ws + 68190208);             // 32 KB (per-row top-8 threshold)
    float* cmax  = (float*)(ws + 68222976);             // 32 KB
    float* cinv  = (float*)(ws + 68255744);             // 32 KB
    unsigned short* VthH = (unsigned short*)(ws + 68288512);  // 2 MB
    unsigned short* VthL = (unsigned short*)(ws + 70385664);  // 2 MB -> ends 72482816
    // pm/pl live only until colred_final; they overlap the part region,
    // which is written only afterwards (stream-ordered).
    const size_t part_off = 72482816;
    float* pm    = (float*)(ws + part_off);             // 1 MB
    float* pl    = (float*)(ws + part_off + 1048576);   // 1 MB
    float* part  = (float*)(ws + part_off);             // ksplit*4 MB

    const size_t part_sz  = (size_t)NB * SEQ * DIM * 4;  // 4 MB
    int ksplit = 1;
    if      (ws_size >= part_off + 8 * part_sz) ksplit = 8;
    else if (ws_size >= part_off + 4 * part_sz) ksplit = 4;
    else if (ws_size >= part_off + 2 * part_sz) ksplit = 2;

    proj_kernel<<<dim3((NB * SEQ) / 16), 256, 0, stream>>>(
        queries, keys, Wql, bql, Wkl, bkl, Wqh, bqh, Wkh, bkh, q_low, k_low, sh);

    vsplit_kernel<<<dim3(SEQ / 32, DIM / 32, NB), 256, 0, stream>>>(
        values, VthH, VthL);

    score_topk10<<<dim3((NB * SEQ) / 8), 256, 0, stream>>>(
        q_low, k_low, valid, Smat, thrv);

    colred_partial<<<dim3(SEQ / 256, 32, NB), 256, 0, stream>>>(
        Smat, thrv, sh, pm, pl);

    colred_final<<<dim3((NB * SEQ) / 256), 256, 0, stream>>>(pm, pl, cmax, cinv);

    if (ksplit == 1) {
        out_mfma<<<dim3(SEQ / QT, 1, NB), 256, 0, stream>>>(
            Smat, VthH, VthL, cmax, cinv, thrv, sh, (float*)d_out, SEQ);
    } else {
        out_mfma<<<dim3(SEQ / QT, ksplit, NB), 256, 0, stream>>>(
            Smat, VthH, VthL, cmax, cinv, thrv, sh, part, SEQ / ksplit);
        reduce_kernel<<<(NB * SEQ * DIM / 4) / 256, 256, 0, stream>>>(
            part, (float*)d_out, ksplit);
    }
}

// Round 12
// 163.520 us; speedup vs baseline: 1.2304x; 1.0249x over previous
//
#include <hip/hip_runtime.h>
#include <float.h>
#include <math.h>

#define SEQ 2048
#define NB 4
#define DIM 128
#define DL 16
#define NEGV (-1e9f)
#define TOPK 8

#define QT 128      // q-rows per out block
#define KC 64       // k chunk staged in LDS (out kernel)
#define QCH 64      // q-chunk for colred

typedef unsigned long long u64;
typedef __attribute__((ext_vector_type(8))) short short8;
typedef __attribute__((ext_vector_type(4))) float f32x4;

__device__ __forceinline__ void top8_insert(float* s, float key) {
    #pragma unroll
    for (int i = 0; i < 8; ++i) {
        float a = s[i];
        s[i] = fmaxf(a, key);
        key  = fminf(a, key);
    }
}

// merge sorted-desc top8s across the 16 lanes of a quad group (xor 1,2,4,8)
__device__ __forceinline__ float top8_merge16(float* s) {
    #pragma unroll
    for (int off = 1; off < 16; off <<= 1) {
        float o[8], t[8];
        #pragma unroll
        for (int i = 0; i < 8; ++i)
            o[i] = __shfl_xor(s[i], off, 64);
        #pragma unroll
        for (int i = 0; i < 8; ++i)
            t[i] = fmaxf(s[i], o[7 - i]);
        #pragma unroll
        for (int i = 0; i < 4; ++i) {
            float a = t[i], c = t[i + 4];
            t[i] = fmaxf(a, c); t[i + 4] = fminf(a, c);
        }
        #pragma unroll
        for (int g2 = 0; g2 < 8; g2 += 4) {
            float a = t[g2], c = t[g2 + 2];
            t[g2] = fmaxf(a, c); t[g2 + 2] = fminf(a, c);
            a = t[g2 + 1]; c = t[g2 + 3];
            t[g2 + 1] = fmaxf(a, c); t[g2 + 3] = fminf(a, c);
        }
        #pragma unroll
        for (int g1 = 0; g1 < 8; g1 += 2) {
            float a = t[g1], c = t[g1 + 1];
            t[g1] = fmaxf(a, c); t[g1 + 1] = fminf(a, c);
        }
        #pragma unroll
        for (int i = 0; i < 8; ++i) s[i] = t[i];
    }
    return s[7];
}

// bf16 round-to-nearest-even of f32 (returns 16-bit pattern)
__device__ __forceinline__ unsigned bf16_rne(float x) {
    unsigned u = __float_as_uint(x);
    return (u + 0x7FFFu + ((u >> 16) & 1u)) >> 16;
}

// ---------------------------------------------------------------------------
// Kernel A: projections. Emits PACKED bf16 MFMA operands for the score GEMM:
//   q = q1+q2+q3 (3-way bf16 split; residual ~2^-25)
//   qA1[row][32] = [q1|q2]   qA2 = [q2|q1]   qA3 = [q1|q3]
//   kB1[col][32] = [k1|k2]   kB2 = [k3|k1]
// so 3 MFMAs give q1k1+q2k2 + q2k1+q1k2 + q1k3+q3k1 (error ~1e-7 rel, same
// as the old fmaf chain). Also sh[k] (per-key high-rank correction).
// ---------------------------------------------------------------------------
__global__ __launch_bounds__(256) void proj_kernel(
    const float* __restrict__ q, const float* __restrict__ k,
    const float* __restrict__ Wql, const float* __restrict__ bql,
    const float* __restrict__ Wkl, const float* __restrict__ bkl,
    const float* __restrict__ Wqh, const float* __restrict__ bqh,
    const float* __restrict__ Wkh, const float* __restrict__ bkh,
    unsigned short* __restrict__ qA1, unsigned short* __restrict__ qA2,
    unsigned short* __restrict__ qA3,
    unsigned short* __restrict__ kB1, unsigned short* __restrict__ kB2,
    float* __restrict__ sh)
{
    __shared__ float Ws[4][DIM * DL];
    __shared__ float rowq[16][DIM];
    __shared__ float rowk[16][DIM];
    int tid = threadIdx.x;
    for (int i = tid; i < DIM * DL; i += 256) {
        Ws[0][i] = Wql[i];
        Ws[1][i] = Wkl[i];
        Ws[2][i] = Wqh[i];
        Ws[3][i] = Wkh[i];
    }
    int r0 = blockIdx.x * 16;
    for (int i = tid; i < 16 * DIM; i += 256) {
        int rr = i >> 7, cc = i & 127;
        rowq[rr][cc] = q[(size_t)(r0 + rr) * DIM + cc];
        rowk[rr][cc] = k[(size_t)(r0 + rr) * DIM + cc];
    }
    __syncthreads();
    int g = tid >> 4;
    int e = tid & 15;
    float aql = 0.f, akl = 0.f, aqh = 0.f, akh = 0.f;
    #pragma unroll 8
    for (int i = 0; i < DIM; ++i) {
        float qv = rowq[g][i], kv = rowk[g][i];
        aql = fmaf(qv, Ws[0][i * DL + e], aql);
        akl = fmaf(kv, Ws[1][i * DL + e], akl);
        aqh = fmaf(qv, Ws[2][i * DL + e], aqh);
        akh = fmaf(kv, Ws[3][i * DL + e], akh);
    }
    int t = r0 + g;
    float qv = aql + bql[e];
    float kv = akl + bkl[e];

    unsigned q1 = bf16_rne(qv);
    float q1f = __uint_as_float(q1 << 16);
    float qr1 = qv - q1f;
    unsigned q2 = bf16_rne(qr1);
    float q2f = __uint_as_float(q2 << 16);
    unsigned q3 = bf16_rne(qr1 - q2f);

    unsigned k1 = bf16_rne(kv);
    float k1f = __uint_as_float(k1 << 16);
    float kr1 = kv - k1f;
    unsigned k2 = bf16_rne(kr1);
    float k2f = __uint_as_float(k2 << 16);
    unsigned k3 = bf16_rne(kr1 - k2f);

    size_t pb = (size_t)t * 32;
    qA1[pb + e] = (unsigned short)q1; qA1[pb + 16 + e] = (unsigned short)q2;
    qA2[pb + e] = (unsigned short)q2; qA2[pb + 16 + e] = (unsigned short)q1;
    qA3[pb + e] = (unsigned short)q1; qA3[pb + 16 + e] = (unsigned short)q3;
    kB1[pb + e] = (unsigned short)k1; kB1[pb + 16 + e] = (unsigned short)k2;
    kB2[pb + e] = (unsigned short)k3; kB2[pb + 16 + e] = (unsigned short)k1;

    float qp = aqh + bqh[e];
    float kp = akh + bkh[e];
    float prod = qp * kp;
    #pragma unroll
    for (int off = 8; off >= 1; off >>= 1)
        prod += __shfl_xor(prod, off, 16);
    if (e == 0) sh[t] = 0.25f * prod;
}

// ---------------------------------------------------------------------------
// Kernel A2: V transpose + bf16 hi/lo split: VthH/VthL[b][d][k].
// ---------------------------------------------------------------------------
__global__ __launch_bounds__(256) void vsplit_kernel(
    const float* __restrict__ V, unsigned short* __restrict__ VH,
    unsigned short* __restrict__ VL)
{
    __shared__ float T[32][33];
    int kb = blockIdx.x * 32, db = blockIdx.y * 32, b = blockIdx.z;
    int tid = threadIdx.x;
    {
        int r = tid >> 3, cg = tid & 7;
        float4 v = *(const float4*)(V + ((size_t)b * SEQ + kb + r) * DIM + db + cg * 4);
        T[r][cg * 4 + 0] = v.x; T[r][cg * 4 + 1] = v.y;
        T[r][cg * 4 + 2] = v.z; T[r][cg * 4 + 3] = v.w;
    }
    __syncthreads();
    int dr = tid >> 3, kg = tid & 7;
    unsigned h[4], l[4];
    #pragma unroll
    for (int j = 0; j < 4; ++j) {
        float f = T[kg * 4 + j][dr];
        unsigned hi = bf16_rne(f);
        float hf = __uint_as_float(hi << 16);
        unsigned lo = bf16_rne(f - hf);
        h[j] = hi; l[j] = lo;
    }
    size_t o = ((size_t)b * DIM + db + dr) * SEQ + kb + kg * 4;
    *(uint2*)(VH + o) = make_uint2(h[0] | (h[1] << 16), h[2] | (h[3] << 16));
    *(uint2*)(VL + o) = make_uint2(l[0] | (l[1] << 16), l[2] | (l[3] << 16));
}

// ---------------------------------------------------------------------------
// Kernel B v11: MFMA score. Block = one 16-row q-tile, 4 waves each covering
// 32 col-tiles (512 cols). Per tile: 2 coalesced B-frag loads + 3 MFMAs
// (16x16x32 bf16, packed 3-way split -> f32-equivalent S), mask, store S,
// per-lane top-8 (4 row-streams). Merge: 16-lane butterfly per quad, then
// cross-wave via 2 KB LDS -> thr[row]. No k_low staging, no pipeline
// barriers, no bank conflicts. A/C lane layouts identical to out_mfma's
// (harness-verified in this code).
// ---------------------------------------------------------------------------
__global__ __launch_bounds__(256) void score_mfma(
    const unsigned short* __restrict__ qA1, const unsigned short* __restrict__ qA2,
    const unsigned short* __restrict__ qA3,
    const unsigned short* __restrict__ kB1, const unsigned short* __restrict__ kB2,
    const int* __restrict__ valid_lens,
    float* __restrict__ Smat, float* __restrict__ thrv)
{
    __shared__ float red[4][16][8];   // [wave][row][top8]

    int tid  = threadIdx.x;
    int lane = tid & 63;
    int wv   = tid >> 6;
    int c15  = lane & 15;
    int g    = lane >> 4;                       // quad
    int row0 = __builtin_amdgcn_readfirstlane(blockIdx.x * 16);
    int b    = row0 >> 11;
    int qi0  = row0 & (SEQ - 1);

    // A fragments (whole kernel): A[row=lane&15][k=quad*8+j]
    size_t aoff = (size_t)(row0 + c15) * 32 + g * 8;
    short8 A1 = *(const short8*)(qA1 + aoff);
    short8 A2 = *(const short8*)(qA2 + aoff);
    short8 A3 = *(const short8*)(qA3 + aoff);

    const unsigned short* kb1 = kB1 + (size_t)b * SEQ * 32;
    const unsigned short* kb2 = kB2 + (size_t)b * SEQ * 32;
    const int* vlb = valid_lens + (size_t)b * SEQ;

    float s8[4][8];
    #pragma unroll
    for (int r = 0; r < 4; ++r)
        #pragma unroll
        for (int i = 0; i < 8; ++i) s8[r][i] = -FLT_MAX;

    int rowg[4];
    #pragma unroll
    for (int r = 0; r < 4; ++r) rowg[r] = qi0 + g * 4 + r;

    for (int ct = wv * 32; ct < wv * 32 + 32; ++ct) {
        int col = ct * 16 + c15;
        size_t boff = (size_t)col * 32 + g * 8;  // B[k=quad*8+j][col]
        short8 B1 = *(const short8*)(kb1 + boff);
        short8 B2 = *(const short8*)(kb2 + boff);

        f32x4 acc = (f32x4){0.f, 0.f, 0.f, 0.f};
        acc = __builtin_amdgcn_mfma_f32_16x16x32_bf16(A1, B1, acc, 0, 0, 0);
        acc = __builtin_amdgcn_mfma_f32_16x16x32_bf16(A2, B1, acc, 0, 0, 0);
        acc = __builtin_amdgcn_mfma_f32_16x16x32_bf16(A3, B2, acc, 0, 0, 0);

        int vl = vlb[col];
        vl = vl < 0 ? 0 : (vl > SEQ - 1 ? SEQ - 1 : vl);

        // C layout: col = lane&15, row = quad*4 + reg
        float* So = Smat + (size_t)(row0 + g * 4) * SEQ + col;
        #pragma unroll
        for (int r = 0; r < 4; ++r) {
            float v = 0.25f * acc[r];
            if (vl == rowg[r]) v += NEGV;
            So[(size_t)r * SEQ] = v;
            top8_insert(s8[r], v);
        }
    }

    // merge the 16 col-slices within each quad (rows g*4+r)
    #pragma unroll
    for (int r = 0; r < 4; ++r) top8_merge16(s8[r]);

    // cross-wave merge via LDS
    if (c15 == 0) {
        #pragma unroll
        for (int r = 0; r < 4; ++r)
            #pragma unroll
            for (int i = 0; i < 8; ++i)
                red[wv][g * 4 + r][i] = s8[r][i];
    }
    __syncthreads();
    if (tid < 16) {
        float fin[8];
        #pragma unroll
        for (int i = 0; i < 8; ++i) fin[i] = red[0][tid][i];
        #pragma unroll
        for (int w2 = 1; w2 < 4; ++w2)
            #pragma unroll
            for (int i = 0; i < 8; ++i)
                top8_insert(fin, red[w2][tid][i]);
        thrv[row0 + tid] = fin[7];
    }
}

// ---------------------------------------------------------------------------
// Kernel C1/C2: column (q-axis) softmax stats over the LAZILY-PATCHED S:
// v_eff = (S >= thr[q]) ? sh[k] : S. Compile-time trip counts (QCH/32).
// ---------------------------------------------------------------------------
__global__ __launch_bounds__(256) void colred_partial(
    const float* __restrict__ Smat, const float* __restrict__ thrv,
    const float* __restrict__ sh,
    float* __restrict__ pm, float* __restrict__ pl)
{
    int kcol = blockIdx.x * 256 + threadIdx.x;
    int qc = blockIdx.y;
    int b  = blockIdx.z;
    const float* Sp  = Smat + (size_t)b * SEQ * SEQ + (size_t)(qc * QCH) * SEQ + kcol;
    const float* thb = thrv + (size_t)b * SEQ + qc * QCH;
    float shk = sh[(size_t)b * SEQ + kcol];
    float m = -FLT_MAX, l = 0.f;
    #pragma unroll 4
    for (int qq = 0; qq < QCH; ++qq) {
        float v = Sp[(size_t)qq * SEQ];
        float t = thb[qq];                 // wave-uniform scalar
        v = (v >= t) ? shk : v;            // lazy top-8 patch
        float nm = fmaxf(m, v);
        l = l * __expf(m - nm) + __expf(v - nm);
        m = nm;
    }
    pm[((size_t)b * 32 + qc) * SEQ + kcol] = m;
    pl[((size_t)b * 32 + qc) * SEQ + kcol] = l;
}

__global__ __launch_bounds__(256) void colred_final(
    const float* __restrict__ pm, const float* __restrict__ pl,
    float* __restrict__ cmax, float* __restrict__ cinv)
{
    int idx = blockIdx.x * 256 + threadIdx.x;
    int b = idx >> 11, kcol = idx & (SEQ - 1);
    float m = -FLT_MAX, l = 0.f;
    #pragma unroll
    for (int c = 0; c < 32; ++c) {
        float mm = pm[((size_t)b * 32 + c) * SEQ + kcol];
        float ll = pl[((size_t)b * 32 + c) * SEQ + kcol];
        float nm = fmaxf(m, mm);
        l = l * __expf(m - nm) + ll * __expf(mm - nm);
        m = nm;
    }
    cmax[idx] = m;
    cinv[idx] = 1.f / l;
}

// ---------------------------------------------------------------------------
// Kernel D (unchanged): MFMA PV with lazy patch.
// ---------------------------------------------------------------------------
__global__ __launch_bounds__(256) void out_mfma(
    const float* __restrict__ Smat, const unsigned short* __restrict__ VH,
    const unsigned short* __restrict__ VL,
    const float* __restrict__ cmax, const float* __restrict__ cinv,
    const float* __restrict__ thrv, const float* __restrict__ sh,
    float* __restrict__ dst, int krange)
{
    __shared__ unsigned int VtH[DIM * 32];   // 16 KB, [d][k-words] XOR-swizzled
    __shared__ unsigned int VtL[DIM * 32];   // 16 KB

    int tid  = threadIdx.x;
    int w    = tid >> 6;
    int lane = tid & 63;
    int ln   = lane & 15;
    int quad = lane >> 4;
    int q0   = blockIdx.x * QT;
    int ksid = blockIdx.y;
    int b    = blockIdx.z;
    int kbeg = ksid * krange;

    const float* Sb = Smat + (size_t)b * SEQ * SEQ;
    const unsigned short* VHb = VH + (size_t)b * DIM * SEQ;
    const unsigned short* VLb = VL + (size_t)b * DIM * SEQ;
    const float* cm  = cmax + (size_t)b * SEQ;
    const float* ci  = cinv + (size_t)b * SEQ;
    const float* shb = sh + (size_t)b * SEQ;

    float thrm[2];
    #pragma unroll
    for (int mt = 0; mt < 2; ++mt)
        thrm[mt] = thrv[(size_t)b * SEQ + q0 + w * 32 + mt * 16 + ln];

    f32x4 acc[2][8];
    #pragma unroll
    for (int mt = 0; mt < 2; ++mt)
        #pragma unroll
        for (int nt = 0; nt < 8; ++nt)
            acc[mt][nt] = (f32x4){0.f, 0.f, 0.f, 0.f};

    int sd0   = tid >> 3;   // staging d row (0..31, +32/iter)
    int skseg = tid & 7;    // staging k-segment (16B granule)

    for (int k0 = kbeg; k0 < kbeg + krange; k0 += KC) {
        // stage V^T hi/lo chunk [128d][64k] bf16, XOR-swizzled 16B granules
        #pragma unroll
        for (int it = 0; it < 4; ++it) {
            int d = sd0 + it * 32;
            size_t go = (size_t)d * SEQ + k0 + skseg * 8;
            uint4 hv = *(const uint4*)(VHb + go);
            uint4 lv = *(const uint4*)(VLb + go);
            int wa = d * 32 + ((skseg ^ (d & 7)) << 2);
            *(uint4*)&VtH[wa] = hv;
            *(uint4*)&VtL[wa] = lv;
        }

        // P A-fragments (registers): lane holds P[q=mtile+ln][k=quad*8+j]
        short8 Ah[2][2], Al[2][2];
        #pragma unroll
        for (int ks = 0; ks < 2; ++ks) {
            int kk = k0 + ks * 32 + quad * 8;
            float4 cma = *(const float4*)(cm + kk);
            float4 cmb = *(const float4*)(cm + kk + 4);
            float4 cia = *(const float4*)(ci + kk);
            float4 cib = *(const float4*)(ci + kk + 4);
            float4 sha = *(const float4*)(shb + kk);
            float4 shx = *(const float4*)(shb + kk + 4);
            #pragma unroll
            for (int mt = 0; mt < 2; ++mt) {
                const float* Sp = Sb + (size_t)(q0 + w * 32 + mt * 16 + ln) * SEQ + kk;
                float4 sa = *(const float4*)Sp;
                float4 sb = *(const float4*)(Sp + 4);
                float t = thrm[mt];
                float e0 = (sa.x >= t) ? sha.x : sa.x;
                float e1 = (sa.y >= t) ? sha.y : sa.y;
                float e2 = (sa.z >= t) ? sha.z : sa.z;
                float e3 = (sa.w >= t) ? sha.w : sa.w;
                float e4 = (sb.x >= t) ? shx.x : sb.x;
                float e5 = (sb.y >= t) ? shx.y : sb.y;
                float e6 = (sb.z >= t) ? shx.z : sb.z;
                float e7 = (sb.w >= t) ? shx.w : sb.w;
                float p[8];
                p[0] = __expf(e0 - cma.x) * cia.x;
                p[1] = __expf(e1 - cma.y) * cia.y;
                p[2] = __expf(e2 - cma.z) * cia.z;
                p[3] = __expf(e3 - cma.w) * cia.w;
                p[4] = __expf(e4 - cmb.x) * cib.x;
                p[5] = __expf(e5 - cmb.y) * cib.y;
                p[6] = __expf(e6 - cmb.z) * cib.z;
                p[7] = __expf(e7 - cmb.w) * cib.w;
                #pragma unroll
                for (int j = 0; j < 8; ++j) {
                    unsigned hi = bf16_rne(p[j]);
                    float hf = __uint_as_float(hi << 16);
                    unsigned lo = bf16_rne(p[j] - hf);
                    Ah[mt][ks][j] = (short)hi;
                    Al[mt][ks][j] = (short)lo;
                }
            }
        }
        __syncthreads();

        #pragma unroll
        for (int nt = 0; nt < 8; ++nt) {
            int d = nt * 16 + ln;
            #pragma unroll
            for (int ks = 0; ks < 2; ++ks) {
                int kseg = ks * 4 + quad;
                int wa = d * 32 + ((kseg ^ (d & 7)) << 2);
                short8 bh = *(short8*)&VtH[wa];
                short8 bl = *(short8*)&VtL[wa];
                #pragma unroll
                for (int mt = 0; mt < 2; ++mt) {
                    acc[mt][nt] = __builtin_amdgcn_mfma_f32_16x16x32_bf16(
                        Ah[mt][ks], bh, acc[mt][nt], 0, 0, 0);
                    acc[mt][nt] = __builtin_amdgcn_mfma_f32_16x16x32_bf16(
                        Al[mt][ks], bh, acc[mt][nt], 0, 0, 0);
                    acc[mt][nt] = __builtin_amdgcn_mfma_f32_16x16x32_bf16(
                        Ah[mt][ks], bl, acc[mt][nt], 0, 0, 0);
                }
            }
        }
        __syncthreads();
    }

    float* dp = dst + (size_t)ksid * ((size_t)NB * SEQ * DIM)
                    + (size_t)b * SEQ * DIM;
    #pragma unroll
    for (int mt = 0; mt < 2; ++mt) {
        #pragma unroll
        for (int r = 0; r < 4; ++r) {
            float* o = dp + (size_t)(q0 + w * 32 + mt * 16 + quad * 4 + r) * DIM + ln;
            #pragma unroll
            for (int nt = 0; nt < 8; ++nt)
                o[nt * 16] = acc[mt][nt][r];
        }
    }
}

__global__ __launch_bounds__(256) void reduce_kernel(
    const float* __restrict__ part, float* __restrict__ out, int ksplit)
{
    int idx = blockIdx.x * 256 + threadIdx.x;
    const float4* p = (const float4*)part;
    float4 a = p[idx];
    for (int s = 1; s < ksplit; ++s) {
        float4 q = p[(size_t)idx + (size_t)s * 262144];
        a.x += q.x; a.y += q.y; a.z += q.z; a.w += q.w;
    }
    ((float4*)out)[idx] = a;
}

extern "C" void kernel_launch(void* const* d_in, const int* in_sizes, int n_in,
                              void* d_out, int out_size, void* d_ws, size_t ws_size,
                              hipStream_t stream)
{
    const float* queries = (const float*)d_in[0];
    const float* keys    = (const float*)d_in[1];
    const float* values  = (const float*)d_in[2];
    const int*   valid   = (const int*)d_in[3];
    const float* Wql = (const float*)d_in[4];
    const float* bql = (const float*)d_in[5];
    const float* Wkl = (const float*)d_in[6];
    const float* bkl = (const float*)d_in[7];
    const float* Wqh = (const float*)d_in[8];
    const float* bqh = (const float*)d_in[9];
    const float* Wkh = (const float*)d_in[10];
    const float* bkh = (const float*)d_in[11];

    char* ws = (char*)d_ws;
    float* Smat = (float*)(ws);                               // 64 MB
    unsigned short* qA1 = (unsigned short*)(ws + 67108864);   // 512 KB
    unsigned short* qA2 = (unsigned short*)(ws + 67633152);   // 512 KB
    unsigned short* qA3 = (unsigned short*)(ws + 68157440);   // 512 KB
    unsigned short* kB1 = (unsigned short*)(ws + 68681728);   // 512 KB
    unsigned short* kB2 = (unsigned short*)(ws + 69206016);   // 512 KB
    float* sh    = (float*)(ws + 69730304);                   // 32 KB
    float* thrv  = (float*)(ws + 69763072);                   // 32 KB
    float* cmax  = (float*)(ws + 69795840);                   // 32 KB
    float* cinv  = (float*)(ws + 69828608);                   // 32 KB
    unsigned short* VthH = (unsigned short*)(ws + 69861376);  // 2 MB
    unsigned short* VthL = (unsigned short*)(ws + 71958528);  // 2 MB -> ends 74055680
    // pm/pl live only until colred_final; they overlap the part region,
    // which is written only afterwards (stream-ordered).
    const size_t part_off = 74055680;
    float* pm    = (float*)(ws + part_off);             // 1 MB
    float* pl    = (float*)(ws + part_off + 1048576);   // 1 MB
    float* part  = (float*)(ws + part_off);             // ksplit*4 MB

    const size_t part_sz  = (size_t)NB * SEQ * DIM * 4;  // 4 MB
    int ksplit = 1;
    if      (ws_size >= part_off + 8 * part_sz) ksplit = 8;
    else if (ws_size >= part_off + 4 * part_sz) ksplit = 4;
    else if (ws_size >= part_off + 2 * part_sz) ksplit = 2;

    proj_kernel<<<dim3((NB * SEQ) / 16), 256, 0, stream>>>(
        queries, keys, Wql, bql, Wkl, bkl, Wqh, bqh, Wkh, bkh,
        qA1, qA2, qA3, kB1, kB2, sh);

    vsplit_kernel<<<dim3(SEQ / 32, DIM / 32, NB), 256, 0, stream>>>(
        values, VthH, VthL);

    score_mfma<<<dim3((NB * SEQ) / 16), 256, 0, stream>>>(
        qA1, qA2, qA3, kB1, kB2, valid, Smat, thrv);

    colred_partial<<<dim3(SEQ / 256, 32, NB), 256, 0, stream>>>(
        Smat, thrv, sh, pm, pl);

    colred_final<<<dim3((NB * SEQ) / 256), 256, 0, stream>>>(pm, pl, cmax, cinv);

    if (ksplit == 1) {
        out_mfma<<<dim3(SEQ / QT, 1, NB), 256, 0, stream>>>(
            Smat, VthH, VthL, cmax, cinv, thrv, sh, (float*)d_out, SEQ);
    } else {
        out_mfma<<<dim3(SEQ / QT, ksplit, NB), 256, 0, stream>>>(
            Smat, VthH, VthL, cmax, cinv, thrv, sh, part, SEQ / ksplit);
        reduce_kernel<<<(NB * SEQ * DIM / 4) / 256, 256, 0, stream>>>(
            part, (float*)d_out, ksplit);
    }
}

// Round 13
// 162.380 us; speedup vs baseline: 1.2391x; 1.0070x over previous
//
#include <hip/hip_runtime.h>
#include <float.h>
#include <math.h>

#define SEQ 2048
#define NB 4
#define DIM 128
#define DL 16
#define NEGV (-1e9f)
#define TOPK 8

#define QT 128      // q-rows per out block
#define KC 64       // k chunk staged in LDS (out kernel)
#define QCH 64      // q-chunk for colred fallback

typedef unsigned long long u64;
typedef __attribute__((ext_vector_type(8))) short short8;
typedef __attribute__((ext_vector_type(4))) float f32x4;

__device__ __forceinline__ void top8_insert(float* s, float key) {
    #pragma unroll
    for (int i = 0; i < 8; ++i) {
        float a = s[i];
        s[i] = fmaxf(a, key);
        key  = fminf(a, key);
    }
}

// merge sorted-desc top8s across the 16 lanes of a quad group (xor 1,2,4,8)
__device__ __forceinline__ float top8_merge16(float* s) {
    #pragma unroll
    for (int off = 1; off < 16; off <<= 1) {
        float o[8], t[8];
        #pragma unroll
        for (int i = 0; i < 8; ++i)
            o[i] = __shfl_xor(s[i], off, 64);
        #pragma unroll
        for (int i = 0; i < 8; ++i)
            t[i] = fmaxf(s[i], o[7 - i]);
        #pragma unroll
        for (int i = 0; i < 4; ++i) {
            float a = t[i], c = t[i + 4];
            t[i] = fmaxf(a, c); t[i + 4] = fminf(a, c);
        }
        #pragma unroll
        for (int g2 = 0; g2 < 8; g2 += 4) {
            float a = t[g2], c = t[g2 + 2];
            t[g2] = fmaxf(a, c); t[g2 + 2] = fminf(a, c);
            a = t[g2 + 1]; c = t[g2 + 3];
            t[g2 + 1] = fmaxf(a, c); t[g2 + 3] = fminf(a, c);
        }
        #pragma unroll
        for (int g1 = 0; g1 < 8; g1 += 2) {
            float a = t[g1], c = t[g1 + 1];
            t[g1] = fmaxf(a, c); t[g1 + 1] = fminf(a, c);
        }
        #pragma unroll
        for (int i = 0; i < 8; ++i) s[i] = t[i];
    }
    return s[7];
}

// bf16 round-to-nearest-even of f32 (returns 16-bit pattern)
__device__ __forceinline__ unsigned bf16_rne(float x) {
    unsigned u = __float_as_uint(x);
    return (u + 0x7FFFu + ((u >> 16) & 1u)) >> 16;
}

// ---------------------------------------------------------------------------
// Kernel A: projections. Emits PACKED bf16 MFMA operands for the score GEMM
// (3-way split, see r12) + sh[k].
// ---------------------------------------------------------------------------
__global__ __launch_bounds__(256) void proj_kernel(
    const float* __restrict__ q, const float* __restrict__ k,
    const float* __restrict__ Wql, const float* __restrict__ bql,
    const float* __restrict__ Wkl, const float* __restrict__ bkl,
    const float* __restrict__ Wqh, const float* __restrict__ bqh,
    const float* __restrict__ Wkh, const float* __restrict__ bkh,
    unsigned short* __restrict__ qA1, unsigned short* __restrict__ qA2,
    unsigned short* __restrict__ qA3,
    unsigned short* __restrict__ kB1, unsigned short* __restrict__ kB2,
    float* __restrict__ sh)
{
    __shared__ float Ws[4][DIM * DL];
    __shared__ float rowq[16][DIM];
    __shared__ float rowk[16][DIM];
    int tid = threadIdx.x;
    for (int i = tid; i < DIM * DL; i += 256) {
        Ws[0][i] = Wql[i];
        Ws[1][i] = Wkl[i];
        Ws[2][i] = Wqh[i];
        Ws[3][i] = Wkh[i];
    }
    int r0 = blockIdx.x * 16;
    for (int i = tid; i < 16 * DIM; i += 256) {
        int rr = i >> 7, cc = i & 127;
        rowq[rr][cc] = q[(size_t)(r0 + rr) * DIM + cc];
        rowk[rr][cc] = k[(size_t)(r0 + rr) * DIM + cc];
    }
    __syncthreads();
    int g = tid >> 4;
    int e = tid & 15;
    float aql = 0.f, akl = 0.f, aqh = 0.f, akh = 0.f;
    #pragma unroll 8
    for (int i = 0; i < DIM; ++i) {
        float qv = rowq[g][i], kv = rowk[g][i];
        aql = fmaf(qv, Ws[0][i * DL + e], aql);
        akl = fmaf(kv, Ws[1][i * DL + e], akl);
        aqh = fmaf(qv, Ws[2][i * DL + e], aqh);
        akh = fmaf(kv, Ws[3][i * DL + e], akh);
    }
    int t = r0 + g;
    float qv = aql + bql[e];
    float kv = akl + bkl[e];

    unsigned q1 = bf16_rne(qv);
    float q1f = __uint_as_float(q1 << 16);
    float qr1 = qv - q1f;
    unsigned q2 = bf16_rne(qr1);
    float q2f = __uint_as_float(q2 << 16);
    unsigned q3 = bf16_rne(qr1 - q2f);

    unsigned k1 = bf16_rne(kv);
    float k1f = __uint_as_float(k1 << 16);
    float kr1 = kv - k1f;
    unsigned k2 = bf16_rne(kr1);
    float k2f = __uint_as_float(k2 << 16);
    unsigned k3 = bf16_rne(kr1 - k2f);

    size_t pb = (size_t)t * 32;
    qA1[pb + e] = (unsigned short)q1; qA1[pb + 16 + e] = (unsigned short)q2;
    qA2[pb + e] = (unsigned short)q2; qA2[pb + 16 + e] = (unsigned short)q1;
    qA3[pb + e] = (unsigned short)q1; qA3[pb + 16 + e] = (unsigned short)q3;
    kB1[pb + e] = (unsigned short)k1; kB1[pb + 16 + e] = (unsigned short)k2;
    kB2[pb + e] = (unsigned short)k3; kB2[pb + 16 + e] = (unsigned short)k1;

    float qp = aqh + bqh[e];
    float kp = akh + bkh[e];
    float prod = qp * kp;
    #pragma unroll
    for (int off = 8; off >= 1; off >>= 1)
        prod += __shfl_xor(prod, off, 16);
    if (e == 0) sh[t] = 0.25f * prod;
}

// ---------------------------------------------------------------------------
// Kernel A2: V transpose + bf16 hi/lo split: VthH/VthL[b][d][k].
// ---------------------------------------------------------------------------
__global__ __launch_bounds__(256) void vsplit_kernel(
    const float* __restrict__ V, unsigned short* __restrict__ VH,
    unsigned short* __restrict__ VL)
{
    __shared__ float T[32][33];
    int kb = blockIdx.x * 32, db = blockIdx.y * 32, b = blockIdx.z;
    int tid = threadIdx.x;
    {
        int r = tid >> 3, cg = tid & 7;
        float4 v = *(const float4*)(V + ((size_t)b * SEQ + kb + r) * DIM + db + cg * 4);
        T[r][cg * 4 + 0] = v.x; T[r][cg * 4 + 1] = v.y;
        T[r][cg * 4 + 2] = v.z; T[r][cg * 4 + 3] = v.w;
    }
    __syncthreads();
    int dr = tid >> 3, kg = tid & 7;
    unsigned h[4], l[4];
    #pragma unroll
    for (int j = 0; j < 4; ++j) {
        float f = T[kg * 4 + j][dr];
        unsigned hi = bf16_rne(f);
        float hf = __uint_as_float(hi << 16);
        unsigned lo = bf16_rne(f - hf);
        h[j] = hi; l[j] = lo;
    }
    size_t o = ((size_t)b * DIM + db + dr) * SEQ + kb + kg * 4;
    *(uint2*)(VH + o) = make_uint2(h[0] | (h[1] << 16), h[2] | (h[3] << 16));
    *(uint2*)(VL + o) = make_uint2(l[0] | (l[1] << 16), l[2] | (l[3] << 16));
}

// ---------------------------------------------------------------------------
// Kernel B v12: MFMA score (r12 structure) + FUSED column partials.
// Pass 1: 3-MFMA packed-split S + per-row top8 -> thr (16-lane butterfly +
// cross-wave LDS merge). Pass 2 (do_stats): each thread owns 8 columns and
// re-reads this block's own 16 S rows (128 KB, L2-hot: written by this block,
// vmcnt(0)-drained at the barrier), applies the lazy patch, and accumulates
// 8 independent online-softmax chains -> pml chunk (128 chunks/batch).
// This deletes colred_partial's 64 MB HBM re-read of S.
// ---------------------------------------------------------------------------
__global__ __launch_bounds__(256) void score_mfma(
    const unsigned short* __restrict__ qA1, const unsigned short* __restrict__ qA2,
    const unsigned short* __restrict__ qA3,
    const unsigned short* __restrict__ kB1, const unsigned short* __restrict__ kB2,
    const int* __restrict__ valid_lens, const float* __restrict__ sh,
    float* __restrict__ Smat, float* __restrict__ thrv,
    float2* __restrict__ pml, int do_stats)
{
    __shared__ float red[4][16][8];   // [wave][row][top8]
    __shared__ float thr_s[16];

    int tid  = threadIdx.x;
    int lane = tid & 63;
    int wv   = tid >> 6;
    int c15  = lane & 15;
    int g    = lane >> 4;                       // quad
    int row0 = __builtin_amdgcn_readfirstlane(blockIdx.x * 16);
    int b    = row0 >> 11;
    int qi0  = row0 & (SEQ - 1);

    // A fragments (whole kernel): A[row=lane&15][k=quad*8+j]
    size_t aoff = (size_t)(row0 + c15) * 32 + g * 8;
    short8 A1 = *(const short8*)(qA1 + aoff);
    short8 A2 = *(const short8*)(qA2 + aoff);
    short8 A3 = *(const short8*)(qA3 + aoff);

    const unsigned short* kb1 = kB1 + (size_t)b * SEQ * 32;
    const unsigned short* kb2 = kB2 + (size_t)b * SEQ * 32;
    const int* vlb = valid_lens + (size_t)b * SEQ;

    float s8[4][8];
    #pragma unroll
    for (int r = 0; r < 4; ++r)
        #pragma unroll
        for (int i = 0; i < 8; ++i) s8[r][i] = -FLT_MAX;

    int rowg[4];
    #pragma unroll
    for (int r = 0; r < 4; ++r) rowg[r] = qi0 + g * 4 + r;

    for (int ct = wv * 32; ct < wv * 32 + 32; ++ct) {
        int col = ct * 16 + c15;
        size_t boff = (size_t)col * 32 + g * 8;  // B[k=quad*8+j][col]
        short8 B1 = *(const short8*)(kb1 + boff);
        short8 B2 = *(const short8*)(kb2 + boff);

        f32x4 acc = (f32x4){0.f, 0.f, 0.f, 0.f};
        acc = __builtin_amdgcn_mfma_f32_16x16x32_bf16(A1, B1, acc, 0, 0, 0);
        acc = __builtin_amdgcn_mfma_f32_16x16x32_bf16(A2, B1, acc, 0, 0, 0);
        acc = __builtin_amdgcn_mfma_f32_16x16x32_bf16(A3, B2, acc, 0, 0, 0);

        int vl = vlb[col];
        vl = vl < 0 ? 0 : (vl > SEQ - 1 ? SEQ - 1 : vl);

        // C layout: col = lane&15, row = quad*4 + reg
        float* So = Smat + (size_t)(row0 + g * 4) * SEQ + col;
        #pragma unroll
        for (int r = 0; r < 4; ++r) {
            float v = 0.25f * acc[r];
            if (vl == rowg[r]) v += NEGV;
            So[(size_t)r * SEQ] = v;
            top8_insert(s8[r], v);
        }
    }

    // merge the 16 col-slices within each quad (rows g*4+r)
    #pragma unroll
    for (int r = 0; r < 4; ++r) top8_merge16(s8[r]);

    // cross-wave merge via LDS
    if (c15 == 0) {
        #pragma unroll
        for (int r = 0; r < 4; ++r)
            #pragma unroll
            for (int i = 0; i < 8; ++i)
                red[wv][g * 4 + r][i] = s8[r][i];
    }
    __syncthreads();   // also drains all S writes (vmcnt(0)) for pass 2
    if (tid < 16) {
        float fin[8];
        #pragma unroll
        for (int i = 0; i < 8; ++i) fin[i] = red[0][tid][i];
        #pragma unroll
        for (int w2 = 1; w2 < 4; ++w2)
            #pragma unroll
            for (int i = 0; i < 8; ++i)
                top8_insert(fin, red[w2][tid][i]);
        thrv[row0 + tid] = fin[7];
        thr_s[tid] = fin[7];
    }

    if (!do_stats) return;
    __syncthreads();

    // ---- pass 2: column (q-axis) softmax partials over this block's 16 rows
    int c0 = tid * 8;
    const float* shb = sh + (size_t)b * SEQ;
    float4 sh_a = *(const float4*)(shb + c0);
    float4 sh_b = *(const float4*)(shb + c0 + 4);
    const float* Srow = Smat + (size_t)row0 * SEQ;

    float mc[8], lc[8];
    #pragma unroll
    for (int i = 0; i < 8; ++i) { mc[i] = -FLT_MAX; lc[i] = 0.f; }

    #pragma unroll 4
    for (int r = 0; r < 16; ++r) {
        float t = thr_s[r];
        float4 va = *(const float4*)(Srow + (size_t)r * SEQ + c0);
        float4 vb = *(const float4*)(Srow + (size_t)r * SEQ + c0 + 4);
        float e[8];
        e[0] = (va.x >= t) ? sh_a.x : va.x;
        e[1] = (va.y >= t) ? sh_a.y : va.y;
        e[2] = (va.z >= t) ? sh_a.z : va.z;
        e[3] = (va.w >= t) ? sh_a.w : va.w;
        e[4] = (vb.x >= t) ? sh_b.x : vb.x;
        e[5] = (vb.y >= t) ? sh_b.y : vb.y;
        e[6] = (vb.z >= t) ? sh_b.z : vb.z;
        e[7] = (vb.w >= t) ? sh_b.w : vb.w;
        #pragma unroll
        for (int i = 0; i < 8; ++i) {
            float nm = fmaxf(mc[i], e[i]);
            lc[i] = lc[i] * __expf(mc[i] - nm) + __expf(e[i] - nm);
            mc[i] = nm;
        }
    }
    int chunk = qi0 >> 4;   // 0..127 within batch
    float2* o = pml + ((size_t)b * 128 + chunk) * SEQ + c0;
    #pragma unroll
    for (int i = 0; i < 8; ++i)
        o[i] = make_float2(mc[i], lc[i]);
}

// ---------------------------------------------------------------------------
// Kernel C (fused path): final column stats over 128 chunks. 128 blocks;
// 4 thread-slices of 32 compile-time-unrolled chunks each + LDS merge.
// ---------------------------------------------------------------------------
__global__ __launch_bounds__(256) void colred_final2(
    const float2* __restrict__ pml,
    float* __restrict__ cmax, float* __restrict__ cinv)
{
    __shared__ float2 red[4][64];
    int tid = threadIdx.x;
    int c0 = tid & 63, sl = tid >> 6;
    int gcol = blockIdx.x * 64 + c0;       // 0..8191
    int b = gcol >> 11, kcol = gcol & (SEQ - 1);
    float m = -FLT_MAX, l = 0.f;
    #pragma unroll 8
    for (int i = 0; i < 32; ++i) {
        int c = sl * 32 + i;
        float2 p = pml[((size_t)b * 128 + c) * SEQ + kcol];
        float nm = fmaxf(m, p.x);
        l = l * __expf(m - nm) + p.y * __expf(p.x - nm);
        m = nm;
    }
    red[sl][c0] = make_float2(m, l);
    __syncthreads();
    if (sl == 0) {
        #pragma unroll
        for (int s = 1; s < 4; ++s) {
            float2 p = red[s][c0];
            float nm = fmaxf(m, p.x);
            l = l * __expf(m - nm) + p.y * __expf(p.x - nm);
            m = nm;
        }
        cmax[gcol] = m;
        cinv[gcol] = 1.f / l;
    }
}

// ---------------------------------------------------------------------------
// Fallback kernels (workspace too small for 8 MB pml): r11's colred pair.
// ---------------------------------------------------------------------------
__global__ __launch_bounds__(256) void colred_partial(
    const float* __restrict__ Smat, const float* __restrict__ thrv,
    const float* __restrict__ sh,
    float* __restrict__ pm, float* __restrict__ pl)
{
    int kcol = blockIdx.x * 256 + threadIdx.x;
    int qc = blockIdx.y;
    int b  = blockIdx.z;
    const float* Sp  = Smat + (size_t)b * SEQ * SEQ + (size_t)(qc * QCH) * SEQ + kcol;
    const float* thb = thrv + (size_t)b * SEQ + qc * QCH;
    float shk = sh[(size_t)b * SEQ + kcol];
    float m = -FLT_MAX, l = 0.f;
    #pragma unroll 4
    for (int qq = 0; qq < QCH; ++qq) {
        float v = Sp[(size_t)qq * SEQ];
        float t = thb[qq];
        v = (v >= t) ? shk : v;
        float nm = fmaxf(m, v);
        l = l * __expf(m - nm) + __expf(v - nm);
        m = nm;
    }
    pm[((size_t)b * 32 + qc) * SEQ + kcol] = m;
    pl[((size_t)b * 32 + qc) * SEQ + kcol] = l;
}

__global__ __launch_bounds__(256) void colred_final(
    const float* __restrict__ pm, const float* __restrict__ pl,
    float* __restrict__ cmax, float* __restrict__ cinv)
{
    int idx = blockIdx.x * 256 + threadIdx.x;
    int b = idx >> 11, kcol = idx & (SEQ - 1);
    float m = -FLT_MAX, l = 0.f;
    #pragma unroll
    for (int c = 0; c < 32; ++c) {
        float mm = pm[((size_t)b * 32 + c) * SEQ + kcol];
        float ll = pl[((size_t)b * 32 + c) * SEQ + kcol];
        float nm = fmaxf(m, mm);
        l = l * __expf(m - nm) + ll * __expf(mm - nm);
        m = nm;
    }
    cmax[idx] = m;
    cinv[idx] = 1.f / l;
}

// ---------------------------------------------------------------------------
// Kernel D (unchanged): MFMA PV with lazy patch.
// ---------------------------------------------------------------------------
__global__ __launch_bounds__(256) void out_mfma(
    const float* __restrict__ Smat, const unsigned short* __restrict__ VH,
    const unsigned short* __restrict__ VL,
    const float* __restrict__ cmax, const float* __restrict__ cinv,
    const float* __restrict__ thrv, const float* __restrict__ sh,
    float* __restrict__ dst, int krange)
{
    __shared__ unsigned int VtH[DIM * 32];   // 16 KB, [d][k-words] XOR-swizzled
    __shared__ unsigned int VtL[DIM * 32];   // 16 KB

    int tid  = threadIdx.x;
    int w    = tid >> 6;
    int lane = tid & 63;
    int ln   = lane & 15;
    int quad = lane >> 4;
    int q0   = blockIdx.x * QT;
    int ksid = blockIdx.y;
    int b    = blockIdx.z;
    int kbeg = ksid * krange;

    const float* Sb = Smat + (size_t)b * SEQ * SEQ;
    const unsigned short* VHb = VH + (size_t)b * DIM * SEQ;
    const unsigned short* VLb = VL + (size_t)b * DIM * SEQ;
    const float* cm  = cmax + (size_t)b * SEQ;
    const float* ci  = cinv + (size_t)b * SEQ;
    const float* shb = sh + (size_t)b * SEQ;

    float thrm[2];
    #pragma unroll
    for (int mt = 0; mt < 2; ++mt)
        thrm[mt] = thrv[(size_t)b * SEQ + q0 + w * 32 + mt * 16 + ln];

    f32x4 acc[2][8];
    #pragma unroll
    for (int mt = 0; mt < 2; ++mt)
        #pragma unroll
        for (int nt = 0; nt < 8; ++nt)
            acc[mt][nt] = (f32x4){0.f, 0.f, 0.f, 0.f};

    int sd0   = tid >> 3;   // staging d row (0..31, +32/iter)
    int skseg = tid & 7;    // staging k-segment (16B granule)

    for (int k0 = kbeg; k0 < kbeg + krange; k0 += KC) {
        // stage V^T hi/lo chunk [128d][64k] bf16, XOR-swizzled 16B granules
        #pragma unroll
        for (int it = 0; it < 4; ++it) {
            int d = sd0 + it * 32;
            size_t go = (size_t)d * SEQ + k0 + skseg * 8;
            uint4 hv = *(const uint4*)(VHb + go);
            uint4 lv = *(const uint4*)(VLb + go);
            int wa = d * 32 + ((skseg ^ (d & 7)) << 2);
            *(uint4*)&VtH[wa] = hv;
            *(uint4*)&VtL[wa] = lv;
        }

        // P A-fragments (registers): lane holds P[q=mtile+ln][k=quad*8+j]
        short8 Ah[2][2], Al[2][2];
        #pragma unroll
        for (int ks = 0; ks < 2; ++ks) {
            int kk = k0 + ks * 32 + quad * 8;
            float4 cma = *(const float4*)(cm + kk);
            float4 cmb = *(const float4*)(cm + kk + 4);
            float4 cia = *(const float4*)(ci + kk);
            float4 cib = *(const float4*)(ci + kk + 4);
            float4 sha = *(const float4*)(shb + kk);
            float4 shx = *(const float4*)(shb + kk + 4);
            #pragma unroll
            for (int mt = 0; mt < 2; ++mt) {
                const float* Sp = Sb + (size_t)(q0 + w * 32 + mt * 16 + ln) * SEQ + kk;
                float4 sa = *(const float4*)Sp;
                float4 sb = *(const float4*)(Sp + 4);
                float t = thrm[mt];
                float e0 = (sa.x >= t) ? sha.x : sa.x;
                float e1 = (sa.y >= t) ? sha.y : sa.y;
                float e2 = (sa.z >= t) ? sha.z : sa.z;
                float e3 = (sa.w >= t) ? sha.w : sa.w;
                float e4 = (sb.x >= t) ? shx.x : sb.x;
                float e5 = (sb.y >= t) ? shx.y : sb.y;
                float e6 = (sb.z >= t) ? shx.z : sb.z;
                float e7 = (sb.w >= t) ? shx.w : sb.w;
                float p[8];
                p[0] = __expf(e0 - cma.x) * cia.x;
                p[1] = __expf(e1 - cma.y) * cia.y;
                p[2] = __expf(e2 - cma.z) * cia.z;
                p[3] = __expf(e3 - cma.w) * cia.w;
                p[4] = __expf(e4 - cmb.x) * cib.x;
                p[5] = __expf(e5 - cmb.y) * cib.y;
                p[6] = __expf(e6 - cmb.z) * cib.z;
                p[7] = __expf(e7 - cmb.w) * cib.w;
                #pragma unroll
                for (int j = 0; j < 8; ++j) {
                    unsigned hi = bf16_rne(p[j]);
                    float hf = __uint_as_float(hi << 16);
                    unsigned lo = bf16_rne(p[j] - hf);
                    Ah[mt][ks][j] = (short)hi;
                    Al[mt][ks][j] = (short)lo;
                }
            }
        }
        __syncthreads();

        #pragma unroll
        for (int nt = 0; nt < 8; ++nt) {
            int d = nt * 16 + ln;
            #pragma unroll
            for (int ks = 0; ks < 2; ++ks) {
                int kseg = ks * 4 + quad;
                int wa = d * 32 + ((kseg ^ (d & 7)) << 2);
                short8 bh = *(short8*)&VtH[wa];
                short8 bl = *(short8*)&VtL[wa];
                #pragma unroll
                for (int mt = 0; mt < 2; ++mt) {
                    acc[mt][nt] = __builtin_amdgcn_mfma_f32_16x16x32_bf16(
                        Ah[mt][ks], bh, acc[mt][nt], 0, 0, 0);
                    acc[mt][nt] = __builtin_amdgcn_mfma_f32_16x16x32_bf16(
                        Al[mt][ks], bh, acc[mt][nt], 0, 0, 0);
                    acc[mt][nt] = __builtin_amdgcn_mfma_f32_16x16x32_bf16(
                        Ah[mt][ks], bl, acc[mt][nt], 0, 0, 0);
                }
            }
        }
        __syncthreads();
    }

    float* dp = dst + (size_t)ksid * ((size_t)NB * SEQ * DIM)
                    + (size_t)b * SEQ * DIM;
    #pragma unroll
    for (int mt = 0; mt < 2; ++mt) {
        #pragma unroll
        for (int r = 0; r < 4; ++r) {
            float* o = dp + (size_t)(q0 + w * 32 + mt * 16 + quad * 4 + r) * DIM + ln;
            #pragma unroll
            for (int nt = 0; nt < 8; ++nt)
                o[nt * 16] = acc[mt][nt][r];
        }
    }
}

__global__ __launch_bounds__(256) void reduce_kernel(
    const float* __restrict__ part, float* __restrict__ out, int ksplit)
{
    int idx = blockIdx.x * 256 + threadIdx.x;
    const float4* p = (const float4*)part;
    float4 a = p[idx];
    for (int s = 1; s < ksplit; ++s) {
        float4 q = p[(size_t)idx + (size_t)s * 262144];
        a.x += q.x; a.y += q.y; a.z += q.z; a.w += q.w;
    }
    ((float4*)out)[idx] = a;
}

extern "C" void kernel_launch(void* const* d_in, const int* in_sizes, int n_in,
                              void* d_out, int out_size, void* d_ws, size_t ws_size,
                              hipStream_t stream)
{
    const float* queries = (const float*)d_in[0];
    const float* keys    = (const float*)d_in[1];
    const float* values  = (const float*)d_in[2];
    const int*   valid   = (const int*)d_in[3];
    const float* Wql = (const float*)d_in[4];
    const float* bql = (const float*)d_in[5];
    const float* Wkl = (const float*)d_in[6];
    const float* bkl = (const float*)d_in[7];
    const float* Wqh = (const float*)d_in[8];
    const float* bqh = (const float*)d_in[9];
    const float* Wkh = (const float*)d_in[10];
    const float* bkh = (const float*)d_in[11];

    char* ws = (char*)d_ws;
    float* Smat = (float*)(ws);                               // 64 MB
    unsigned short* qA1 = (unsigned short*)(ws + 67108864);   // 512 KB
    unsigned short* qA2 = (unsigned short*)(ws + 67633152);   // 512 KB
    unsigned short* qA3 = (unsigned short*)(ws + 68157440);   // 512 KB
    unsigned short* kB1 = (unsigned short*)(ws + 68681728);   // 512 KB
    unsigned short* kB2 = (unsigned short*)(ws + 69206016);   // 512 KB
    float* sh    = (float*)(ws + 69730304);                   // 32 KB
    float* thrv  = (float*)(ws + 69763072);                   // 32 KB
    float* cmax  = (float*)(ws + 69795840);                   // 32 KB
    float* cinv  = (float*)(ws + 69828608);                   // 32 KB
    unsigned short* VthH = (unsigned short*)(ws + 69861376);  // 2 MB
    unsigned short* VthL = (unsigned short*)(ws + 71958528);  // 2 MB -> ends 74055680
    // pml (8 MB, fused path) lives only until colred_final2; it overlaps the
    // part region, which is written only afterwards (stream-ordered).
    const size_t part_off = 74055680;
    float2* pml  = (float2*)(ws + part_off);            // 8 MB (fused)
    float* pm    = (float*)(ws + part_off);             // 1 MB (fallback)
    float* pl    = (float*)(ws + part_off + 1048576);   // 1 MB (fallback)
    float* part  = (float*)(ws + part_off);             // ksplit*4 MB

    const size_t part_sz  = (size_t)NB * SEQ * DIM * 4;  // 4 MB
    int ksplit = 1;
    if      (ws_size >= part_off + 8 * part_sz) ksplit = 8;
    else if (ws_size >= part_off + 4 * part_sz) ksplit = 4;
    else if (ws_size >= part_off + 2 * part_sz) ksplit = 2;

    int fused = (ws_size >= part_off + 8388608) ? 1 : 0;

    proj_kernel<<<dim3((NB * SEQ) / 16), 256, 0, stream>>>(
        queries, keys, Wql, bql, Wkl, bkl, Wqh, bqh, Wkh, bkh,
        qA1, qA2, qA3, kB1, kB2, sh);

    vsplit_kernel<<<dim3(SEQ / 32, DIM / 32, NB), 256, 0, stream>>>(
        values, VthH, VthL);

    score_mfma<<<dim3((NB * SEQ) / 16), 256, 0, stream>>>(
        qA1, qA2, qA3, kB1, kB2, valid, sh, Smat, thrv, pml, fused);

    if (fused) {
        colred_final2<<<dim3((NB * SEQ) / 64), 256, 0, stream>>>(pml, cmax, cinv);
    } else {
        colred_partial<<<dim3(SEQ / 256, 32, NB), 256, 0, stream>>>(
            Smat, thrv, sh, pm, pl);
        colred_final<<<dim3((NB * SEQ) / 256), 256, 0, stream>>>(pm, pl, cmax, cinv);
    }

    if (ksplit == 1) {
        out_mfma<<<dim3(SEQ / QT, 1, NB), 256, 0, stream>>>(
            Smat, VthH, VthL, cmax, cinv, thrv, sh, (float*)d_out, SEQ);
    } else {
        out_mfma<<<dim3(SEQ / QT, ksplit, NB), 256, 0, stream>>>(
            Smat, VthH, VthL, cmax, cinv, thrv, sh, part, SEQ / ksplit);
        reduce_kernel<<<(NB * SEQ * DIM / 4) / 256, 256, 0, stream>>>(
            part, (float*)d_out, ksplit);
    }
}